// Round 10
// baseline (434.219 us; speedup 1.0000x reference)
//
#include <hip/hip_runtime.h>
#include <math.h>

// Problem constants
#define B_      32
#define S_      512
#define H_      256
#define EMB_    256
#define M_      (B_*S_)     // 16384
#define N7_     1792        // 7*H
#define NG_     2048        // reordered gate width
#define NS_     2560        // smalls: 2048 reordered + 512 fo
#define KA_     1024        // augmented K: 3H (shifted h) + EMB (emb)
#define LABEL_  16

// Layer GEMM tile
#define BM 256
#define BN 256
#define BK 64
#define NT (KA_/BK)         // 16 K-tiles
#define EBM 64

typedef __bf16 bf16x8 __attribute__((ext_vector_type(8)));
typedef float  f32x4  __attribute__((ext_vector_type(4)));
typedef unsigned short us8 __attribute__((ext_vector_type(8)));

__device__ __forceinline__ float sigf(float x){ return 1.f/(1.f+__expf(-x)); }

__device__ __forceinline__ unsigned short f2bf(float f){
    union { float f; unsigned int u; } v; v.f = f;
    unsigned int r = v.u + 0x7FFFu + ((v.u >> 16) & 1u);   // RNE
    return (unsigned short)(r >> 16);
}
__device__ __forceinline__ float bf2f(unsigned short u){
    union { unsigned int i; float f; } v; v.i = ((unsigned int)u) << 16; return v.f;
}

// ---------------------------------------------------------------------------
// Merged prep.  WaugT threads remapped for read-coalescing: thread u handles
// (j = u & 2047, kb = (u>>11)*32) -> a wave covers 64 consecutive j (cols in
// 4 clusters of 16 consecutive) and each thread writes one full 64B line.
#define WAUG_TH (NG_*(KA_/32))           // 65536
#define WPT_TH  (H_*EMB_/8)              // 8192
#define EMB_TH  (M_*EMB_/8)              // 524288
#define PREP_TH (WAUG_TH + WPT_TH + EMB_TH)

__global__ void prep_all(const float* __restrict__ Ws, const float* __restrict__ Us,
                         const float* __restrict__ ugu, const float* __restrict__ Wp,
                         const int* __restrict__ idx, const float* __restrict__ E,
                         unsigned short* __restrict__ WaugT, unsigned short* __restrict__ WpT,
                         unsigned short* __restrict__ embbf, unsigned short* __restrict__ zpage){
    long u = (long)blockIdx.x*256 + threadIdx.x;
    if(u < 512) zpage[u] = 0;
    if(u < WAUG_TH){
        int j  = (int)u & (NG_-1);
        int kb = ((int)u >> 11) * 32;
        int tg = j >> 7, rem = j & 127, p = rem >> 4, t = tg*16 + (rem & 15);
        us8 o[4];
        if(p < 7){
            int col = p*256 + t;
            #pragma unroll
            for(int c=0;c<4;c++)
                #pragma unroll
                for(int x=0;x<8;x++){
                    int k = kb + c*8 + x;
                    float v = (k < 768) ? Ws[(long)k*N7_ + col] : Us[(long)(k-768)*N7_ + col];
                    o[c][x] = f2bf(v);
                }
        } else {
            #pragma unroll
            for(int c=0;c<4;c++)
                #pragma unroll
                for(int x=0;x<8;x++){
                    int k = kb + c*8 + x;
                    float v = (k >= 256 && k < 512) ? ugu[(k-256)*H_ + t] : 0.f;
                    o[c][x] = f2bf(v);
                }
        }
        #pragma unroll
        for(int c=0;c<4;c++) *(us8*)&WaugT[(long)j*KA_ + kb + c*8] = o[c];
    } else if(u < WAUG_TH + WPT_TH){
        long v = u - WAUG_TH;
        int j = (int)(v >> 5), kc = ((int)v & 31)*8;
        us8 o;
        #pragma unroll
        for(int x=0;x<8;x++) o[x] = f2bf(Wp[(long)(kc+x)*H_ + j]);
        *(us8*)&WpT[(long)j*EMB_ + kc] = o;
    } else if(u < PREP_TH){
        long v = u - WAUG_TH - WPT_TH;
        int i = (int)(v >> 5), kc = ((int)v & 31)*8;
        const float* src = E + (size_t)idx[i]*EMB_ + kc;
        us8 o;
        #pragma unroll
        for(int x=0;x<8;x++) o[x] = f2bf(src[x]);
        *(us8*)&embbf[(size_t)i*EMB_ + kc] = o;
    }
}

// ---------------------------------------------------------------------------
// Embed projection via MFMA: h0(bf16) = c0(f32) = (embbf @ WpT^T + bp) * mask
__global__ __launch_bounds__(256, 2) void embed_mfma(
        const unsigned short* __restrict__ embbf, const unsigned short* __restrict__ WpT,
        const float* __restrict__ bp, const float* __restrict__ mask,
        unsigned short* __restrict__ h0b, float* __restrict__ c0){
    __shared__ unsigned short As[2][EBM*32];   //  4 KB x2
    __shared__ unsigned short Bs[2][H_*32];    // 16 KB x2
    int tid = threadIdx.x, w = tid>>6, l = tid&63, fr = l&15, fq = l>>4;
    int m0 = blockIdx.x * EBM;
    f32x4 acc[4][4];
    #pragma unroll
    for(int m=0;m<4;m++)
        #pragma unroll
        for(int n=0;n<4;n++) acc[m][n] = (f32x4){0.f,0.f,0.f,0.f};

    auto stage = [&](int buf, int kt){
        {
            int row = tid >> 2;
            int k0 = ((tid & 3) ^ ((row >> 1) & 3)) * 8;
            const unsigned short* src = embbf + (size_t)(m0+row)*EMB_ + kt + k0;
            __builtin_amdgcn_global_load_lds(
                (const __attribute__((address_space(1))) unsigned int*)src,
                (__attribute__((address_space(3))) unsigned int*)(&As[buf][w*512]),
                16, 0, 0);
        }
        #pragma unroll
        for(int q=0;q<4;q++){
            int v = q*256 + tid;
            int col = v >> 2;
            int k0 = ((v & 3) ^ ((col >> 1) & 3)) * 8;
            const unsigned short* src = WpT + (size_t)col*EMB_ + kt + k0;
            __builtin_amdgcn_global_load_lds(
                (const __attribute__((address_space(1))) unsigned int*)src,
                (__attribute__((address_space(3))) unsigned int*)(&Bs[buf][(q*256 + w*64)*8]),
                16, 0, 0);
        }
    };

    stage(0, 0);
    __syncthreads();
    int cur = 0;
    for(int step=0; step<EMB_/32; step++){
        if(step+1 < EMB_/32) stage(cur^1, (step+1)*32);
        bf16x8 bfv[4];
        #pragma unroll
        for(int n=0;n<4;n++){
            int colr = w*64 + n*16 + fr;
            int slot = fq ^ ((colr >> 1) & 3);
            bfv[n] = *(const bf16x8*)(&Bs[cur][colr*32 + slot*8]);
        }
        #pragma unroll
        for(int m=0;m<4;m++){
            int rowr = m*16 + fr;
            int slot = fq ^ ((rowr >> 1) & 3);
            bf16x8 af = *(const bf16x8*)(&As[cur][rowr*32 + slot*8]);
            #pragma unroll
            for(int n=0;n<4;n++)
                acc[m][n] = __builtin_amdgcn_mfma_f32_16x16x32_bf16(af, bfv[n], acc[m][n], 0,0,0);
        }
        __syncthreads();
        cur ^= 1;
    }
    #pragma unroll
    for(int m=0;m<4;m++){
        #pragma unroll
        for(int j=0;j<4;j++){
            int i = m0 + m*16 + fq*4 + j;
            float mk = mask[i];
            #pragma unroll
            for(int n=0;n<4;n++){
                int col = w*64 + n*16 + fr;
                float v = (acc[m][n][j] + bp[col]) * mk;
                h0b[(size_t)i*H_ + col] = f2bf(v);
                c0 [(size_t)i*H_ + col] = v;
            }
        }
    }
}

// ---------------------------------------------------------------------------
// mean over S of bf16 h (used once, for h0): outA/outB[b,h]
__global__ void reduce_mean_s(const unsigned short* __restrict__ h, float* __restrict__ outA,
                              float* __restrict__ outB){
    __shared__ float part[4][256];
    int b = blockIdx.x;
    int hh = threadIdx.x & 255, sg = threadIdx.x >> 8;
    float s = 0.f;
    long base = ((long)b*S_ + sg*128)*H_ + hh;
    for(int ss=0; ss<128; ss++) s += bf2f(h[base + (long)ss*H_]);
    part[sg][hh] = s;
    __syncthreads();
    if(threadIdx.x < 256){
        float t = (part[0][hh]+part[1][hh]+part[2][hh]+part[3][hh]) * (1.f/S_);
        outA[b*H_+hh] = t;
        if(outB) outB[b*H_+hh] = t;
    }
}

// ---------------------------------------------------------------------------
// smalls v2: weight-reuse.  Grid (NS/256, 4); each block handles 8 batches
// for one 256-col slice; g/havg for the 8 batches staged in LDS; every
// weight element read once per 8 batches.  k ascending per output (as before).
__global__ void small_gemm2(const float* __restrict__ g, const float* __restrict__ havg,
                            const float* __restrict__ Vs, const float* __restrict__ bVs,
                            const float* __restrict__ Wgw, const float* __restrict__ bgu,
                            const float* __restrict__ WgW, const float* __restrict__ UgU,
                            const float* __restrict__ bgU, float* __restrict__ smalls){
    __shared__ float gs[8][256], hs[8][256];
    int t0 = threadIdx.x;
    int b0 = blockIdx.y * 8;
    #pragma unroll
    for(int q=0;q<8;q++){
        gs[q][t0] = g[(b0+q)*H_ + t0];
        hs[q][t0] = havg[(b0+q)*H_ + t0];
    }
    __syncthreads();
    int j = blockIdx.x*256 + t0;
    float acc[8];
    if(j < NG_){
        int tg = j >> 7, rem = j & 127, p = rem >> 4, t = tg*16 + (rem & 15);
        if(p < 7){
            int col = p*256 + t;
            #pragma unroll
            for(int q=0;q<8;q++) acc[q] = bVs[col];
            for(int k=0;k<H_;k++){
                float wv = Vs[k*N7_+col];
                #pragma unroll
                for(int q=0;q<8;q++) acc[q] += gs[q][k]*wv;
            }
        } else {
            #pragma unroll
            for(int q=0;q<8;q++) acc[q] = bgu[t];
            for(int k=0;k<H_;k++){
                float wv = Wgw[k*H_+t];
                #pragma unroll
                for(int q=0;q<8;q++) acc[q] += gs[q][k]*wv;
            }
        }
        #pragma unroll
        for(int q=0;q<8;q++) smalls[(b0+q)*NS_ + j] = acc[q];
    } else {
        int jj = j - NG_;
        #pragma unroll
        for(int q=0;q<8;q++) acc[q] = bgU[jj];
        for(int k=0;k<H_;k++){
            float w1 = WgW[k*512+jj], w2 = UgU[k*512+jj];
            #pragma unroll
            for(int q=0;q<8;q++) acc[q] += gs[q][k]*w1 + hs[q][k]*w2;
        }
        #pragma unroll
        for(int q=0;q<8;q++) smalls[(b0+q)*NS_ + j] = sigf(acc[q]);
    }
}

// ---------------------------------------------------------------------------
// MFMA gates-GEMM (M=16384, N=2048, K=1024).  256x256x64 tiles, 512 thr /
// 8 waves.  Grid transposed (A L2-local); incremental staging pointers.
// EXACT r8 main loop: fine per-phase interleave, vmcnt(0) at tile entry,
// stage halves 0..3 inside phases, both sched_barriers.  Fused SCell
// epilogue + GCell/h-mean partial reductions.
__global__ __launch_bounds__(512, 2) void layer_mfma(
        const unsigned short* __restrict__ hbf, const unsigned short* __restrict__ embbf,
        const unsigned short* __restrict__ WaugT, const unsigned short* __restrict__ zpage,
        const float* __restrict__ c_old, const float* __restrict__ cg_old,
        const float* __restrict__ smalls, const float* __restrict__ mask,
        unsigned short* __restrict__ hbf_new, float* __restrict__ c_new,
        float* __restrict__ lpart, float* __restrict__ apart, float* __restrict__ hpart){
    __shared__ unsigned short As[2][BM*BK];   // 32 KB x2
    __shared__ unsigned short Bs[2][BN*BK];   // 32 KB x2
    __shared__ float red[8][16][3];
    int tid = threadIdx.x;
    int w = tid >> 6, l = tid & 63;
    int fr = l & 15, fq = l >> 4;
    int wr = w >> 1, wcl = w & 1;             // wave = rows wr*64.., cols wcl*128..
    int m0 = blockIdx.x * BM;                 // grid transposed: x = M-panel
    int n0 = blockIdx.y * BN;
    int b  = m0 >> 9;

    f32x4 acc[4][8];
    #pragma unroll
    for(int m=0;m<4;m++)
        #pragma unroll
        for(int n=0;n<8;n++) acc[m][n] = (f32x4){0.f,0.f,0.f,0.f};

    // ---- hoisted per-thread staging geometry
    int rowc[2][2], k0a[2][2];
    #pragma unroll
    for(int p=0;p<2;p++)
        #pragma unroll
        for(int q=0;q<2;q++){
            int u = q*512 + tid;
            int row = p*128 + (u>>3);
            rowc[p][q] = row;
            k0a[p][q]  = ((u & 7) ^ (row & 7)) * 8;
        }
    const unsigned short* srcA[2][2];
    const unsigned short* srcB[2][2];
    #pragma unroll
    for(int hf=0;hf<2;hf++)
        #pragma unroll
        for(int q=0;q<2;q++){
            int u = q*512 + tid;
            int col = hf*128 + (u>>3);
            int k0 = ((u & 7) ^ (col & 7)) * 8;
            srcB[hf][q] = WaugT + (size_t)(n0 + col)*KA_ + k0;
        }
    auto setupA = [&](int r){
        #pragma unroll
        for(int p=0;p<2;p++)
            #pragma unroll
            for(int q=0;q<2;q++){
                int i = m0 + rowc[p][q];
                if(r < 3){
                    int si = (i & (S_-1)) + r - 1;
                    srcA[p][q] = ((unsigned)si < (unsigned)S_)
                               ? hbf + (size_t)(i + r - 1)*H_ + k0a[p][q]
                               : zpage + k0a[p][q];
                } else {
                    srcA[p][q] = embbf + (size_t)i*EMB_ + k0a[p][q];
                }
            }
    };
    auto advance = [&](){
        #pragma unroll
        for(int p=0;p<2;p++)
            #pragma unroll
            for(int q=0;q<2;q++){ srcA[p][q] += BK; srcB[p][q] += BK; }
    };
    auto stage_half = [&](int buf, int ph){   // ph 0,1 = A halves; 2,3 = B halves
        if(ph < 2){
            #pragma unroll
            for(int q=0;q<2;q++)
                __builtin_amdgcn_global_load_lds(
                    (const __attribute__((address_space(1))) unsigned int*)srcA[ph][q],
                    (__attribute__((address_space(3))) unsigned int*)
                        (&As[buf][ph*8192 + (q*512 + w*64)*8]),
                    16, 0, 0);
        } else {
            int hf = ph - 2;
            #pragma unroll
            for(int q=0;q<2;q++)
                __builtin_amdgcn_global_load_lds(
                    (const __attribute__((address_space(1))) unsigned int*)srcB[hf][q],
                    (__attribute__((address_space(3))) unsigned int*)
                        (&Bs[buf][hf*8192 + (q*512 + w*64)*8]),
                    16, 0, 0);
        }
    };

    // prologue: stage tile 0 fully into buf 0; pointers -> tile 1
    setupA(0);
    stage_half(0, 0); stage_half(0, 1); stage_half(0, 2); stage_half(0, 3);
    advance();

    bf16x8 afv[4];
    #pragma unroll 1
    for(int t=0; t<NT; ++t){
        int buf = t & 1;
        int st  = t + 1;                    // tile being staged this iter
        #pragma unroll
        for(int p=0;p<4;p++){
            int ks = p >> 1, nh = p & 1;    // kslice, n-half
            if(p == 0){
                // all 4 halves of tile t must have landed before any read
                asm volatile("s_waitcnt vmcnt(0)" ::: "memory");
                __builtin_amdgcn_s_barrier();
            }
            // 1) ds_read this phase's quadrant fragments
            if(nh == 0){
                #pragma unroll
                for(int m=0;m<4;m++){
                    int row  = wr*64 + m*16 + fr;
                    int slot = (ks*4 + fq) ^ (row & 7);
                    afv[m] = *(const bf16x8*)(&As[buf][row*BK + slot*8]);
                }
            }
            bf16x8 bfv[4];
            #pragma unroll
            for(int nn=0;nn<4;nn++){
                int col  = wcl*128 + (nh*4+nn)*16 + fr;
                int slot = (ks*4 + fq) ^ (col & 7);
                bfv[nn] = *(const bf16x8*)(&Bs[buf][col*BK + slot*8]);
            }
            // 2) stage one half-tile of t+1
            if(st < NT){
                if(p == 0 && (st & 3) == 0) setupA(st >> 2);
                stage_half(buf^1, p);
            }
            // 3) phase barrier
            __builtin_amdgcn_s_barrier();
            // 4) wait own ds_reads; fence MFMA below the wait (rule #18)
            asm volatile("s_waitcnt lgkmcnt(0)" ::: "memory");
            __builtin_amdgcn_sched_barrier(0);
            // 5) MFMA cluster on (ks, nh)
            __builtin_amdgcn_s_setprio(1);
            #pragma unroll
            for(int m=0;m<4;m++)
                #pragma unroll
                for(int nn=0;nn<4;nn++)
                    acc[m][nh*4+nn] = __builtin_amdgcn_mfma_f32_16x16x32_bf16(
                                          afv[m], bfv[nn], acc[m][nh*4+nn], 0,0,0);
            __builtin_amdgcn_s_setprio(0);
            __builtin_amdgcn_sched_barrier(0);
            // 6) phase barrier
            __builtin_amdgcn_s_barrier();
        }
        if(st < NT) advance();
    }

    // ---- fused SCell epilogue + GCell/h-mean partial reductions
    int t = (n0 >> 3) + wcl*16 + fr;
    float sm[8];
    #pragma unroll
    for(int n=0;n<8;n++) sm[n] = smalls[b*NS_ + n0 + wcl*128 + n*16 + fr];
    float cgv = cg_old[b*H_ + t];
    float lsum = 0.f, asum = 0.f, hsum = 0.f;
    #pragma unroll
    for(int m=0;m<4;m++){
        #pragma unroll
        for(int j=0;j<4;j++){
            int i = m0 + wr*64 + m*16 + fq*4 + j;
            int s = i & (S_-1);
            float gv[8];
            #pragma unroll
            for(int n=0;n<8;n++) gv[n] = acc[m][n][j] + sm[n];
            float ei=__expf(sigf(gv[0])), el=__expf(sigf(gv[1])), er=__expf(sigf(gv[2]));
            float ef=__expf(sigf(gv[3])), es=__expf(sigf(gv[4]));
            float inv = 1.f/(ei+el+er+ef+es);
            float c0v = c_old[(size_t)i*H_ + t];
            float cbv = (s>0)      ? c_old[(size_t)(i-1)*H_ + t] : 0.f;
            float cav = (s<S_-1)   ? c_old[(size_t)(i+1)*H_ + t] : 0.f;
            float tu = tanhf(gv[6]);
            float nc = (cbv*el + c0v*ef + er*cav + es*cgv + ei*tu)*inv;
            float nh2 = gv[5]*tanhf(nc);
            float mk = mask[i];
            float ncm = nc*mk, nhm = nh2*mk;
            c_new [(size_t)i*H_ + t] = ncm;
            hbf_new[(size_t)i*H_ + t] = f2bf(nhm);
            float e = __expf(sigf(gv[7]) - (1.f - mk)*1e16f);
            lsum += e;
            asum += e*c0v;
            hsum += nhm;
        }
    }
    #pragma unroll
    for(int off=16; off<64; off<<=1){
        lsum += __shfl_xor(lsum, off);
        asum += __shfl_xor(asum, off);
        hsum += __shfl_xor(hsum, off);
    }
    if(l < 16){ red[w][l][0]=lsum; red[w][l][1]=asum; red[w][l][2]=hsum; }
    __syncthreads();
    if(tid < 32){
        int wc2 = tid >> 4, fr2 = tid & 15;
        float L = 0.f, A = 0.f, Hh = 0.f;
        #pragma unroll
        for(int k=0;k<4;k++){
            L  += red[2*k + wc2][fr2][0];
            A  += red[2*k + wc2][fr2][1];
            Hh += red[2*k + wc2][fr2][2];
        }
        int tt = (n0 >> 3) + wc2*16 + fr2;
        int by = blockIdx.x;                // m-panel (grid transposed)
        lpart[by*H_ + tt] = L;
        apart[by*H_ + tt] = A;
        hpart[by*H_ + tt] = Hh;
    }
}

// ---------------------------------------------------------------------------
// Combine per-row-chunk partials: g_new, cg_new, havg (mean of h_new over S).
__global__ void gcell2x(const float* __restrict__ lpart, const float* __restrict__ apart,
                        const float* __restrict__ hpart, const float* __restrict__ cg_old,
                        const float* __restrict__ smalls,
                        float* __restrict__ g_new, float* __restrict__ cg_new,
                        float* __restrict__ havg_out){
    int b = blockIdx.x, t = threadIdx.x;
    float L = 0.f, A = 0.f, Hs = 0.f;
    for(int ci=0; ci<2; ci++){
        int by = b*2 + ci;
        L  += lpart[by*H_ + t];
        A  += apart[by*H_ + t];
        Hs += hpart[by*H_ + t];
    }
    float fg = smalls[b*NS_ + NG_ + t];
    float og = smalls[b*NS_ + NG_ + 256 + t];
    float ncg = fg*cg_old[b*H_+t] + A/L;
    g_new[b*H_+t]    = og*tanhf(ncg);
    cg_new[b*H_+t]   = ncg;
    havg_out[b*H_+t] = Hs * (1.f/S_);
}

// ---------------------------------------------------------------------------
// out[0:512] = g@Wo + bo ; out[512:528] = mean over b of the first part
__global__ void outk(const float* __restrict__ g, const float* __restrict__ Wo,
                     const float* __restrict__ bo, float* __restrict__ out){
    __shared__ float o1[B_*LABEL_];
    int t = threadIdx.x;
    if(t < B_*LABEL_){
        int b = t/LABEL_, j = t%LABEL_;
        float acc = bo[j];
        for(int k=0;k<H_;k++) acc += g[b*H_+k]*Wo[k*LABEL_+j];
        o1[t] = acc;
        out[t] = acc;
    }
    __syncthreads();
    if(t < LABEL_){
        float s = 0.f;
        for(int b=0;b<B_;b++) s += o1[b*LABEL_+t];
        out[B_*LABEL_+t] = s*(1.f/B_);
    }
}

// ---------------------------------------------------------------------------
extern "C" void kernel_launch(void* const* d_in, const int* in_sizes, int n_in,
                              void* d_out, int out_size, void* d_ws, size_t ws_size,
                              hipStream_t stream){
    const int*   node_text = (const int*)  d_in[2];
    const float* word_mask = (const float*)d_in[3];
    const float* E   = (const float*)d_in[7];
    const float* Wp  = (const float*)d_in[8];
    const float* bp  = (const float*)d_in[9];
    const float* Ws  = (const float*)d_in[10];
    const float* Us  = (const float*)d_in[11];
    const float* Vs  = (const float*)d_in[12];
    const float* bVs = (const float*)d_in[13];
    const float* WgW = (const float*)d_in[14];
    const float* Wgw = (const float*)d_in[15];
    const float* UgU = (const float*)d_in[16];
    const float* bgU = (const float*)d_in[17];
    const float* ugu = (const float*)d_in[18];
    const float* bgu = (const float*)d_in[19];
    const float* Wo  = (const float*)d_in[20];
    const float* bo  = (const float*)d_in[21];

    float* w = (float*)d_ws;
    size_t off = 0;
    auto alloc = [&](size_t nfloats){ float* p = w + off; off += nfloats; return p; };
    unsigned short* WaugT = (unsigned short*)alloc((size_t)NG_*KA_/2);   // 4 MB
    unsigned short* zpage = (unsigned short*)alloc(256);                  // 1 KB zeros
    unsigned short* WpT   = (unsigned short*)alloc((size_t)H_*EMB_/2);   // 128 KB
    unsigned short* embbf = (unsigned short*)alloc((size_t)M_*EMB_/2);   // 8.4 MB
    unsigned short* hbf[2] = { (unsigned short*)alloc((size_t)M_*H_/2),
                               (unsigned short*)alloc((size_t)M_*H_/2) };
    float* cb[2]  = { alloc((size_t)M_*H_), alloc((size_t)M_*H_) };     // 16.8 MB each
    float* lpart  = alloc((size_t)(M_/BM)*H_);
    float* apart  = alloc((size_t)(M_/BM)*H_);
    float* hpart  = alloc((size_t)(M_/BM)*H_);
    float* gb[2]  = { alloc(B_*H_), alloc(B_*H_) };
    float* cgb[2] = { alloc(B_*H_), alloc(B_*H_) };
    float* havg   = alloc(B_*H_);
    float* smalls = alloc((size_t)B_*NS_);
    // total ~ 62 MB

    prep_all<<<(PREP_TH + 255)/256, 256, 0, stream>>>(Ws, Us, ugu, Wp, node_text, E,
                                                      WaugT, WpT, embbf, zpage);
    embed_mfma<<<M_/EBM, 256, 0, stream>>>(embbf, WpT, bp, word_mask, hbf[0], cb[0]);
    reduce_mean_s<<<B_, 1024, 0, stream>>>(hbf[0], gb[0], cgb[0]);

    int cur = 0;
    for(int layer=0; layer<3; layer++){
        int nxt = cur ^ 1;
        const float* havg_in = (layer == 0) ? gb[0] : havg;
        small_gemm2<<<dim3(NS_/256, 4), 256, 0, stream>>>(gb[cur], havg_in, Vs, bVs,
                                                          Wgw, bgu, WgW, UgU, bgU, smalls);
        layer_mfma<<<dim3(M_/BM, NG_/BN), 512, 0, stream>>>(hbf[cur], embbf, WaugT, zpage,
                                                            cb[cur], cgb[cur], smalls, word_mask,
                                                            hbf[nxt], cb[nxt],
                                                            lpart, apart, hpart);
        gcell2x<<<B_, 256, 0, stream>>>(lpart, apart, hpart, cgb[cur], smalls,
                                        gb[nxt], cgb[nxt], havg);
        cur = nxt;
    }
    outk<<<1, 512, 0, stream>>>(gb[cur], Wo, bo, (float*)d_out);
}

// Round 11
// 412.907 us; speedup vs baseline: 1.0516x; 1.0516x over previous
//
#include <hip/hip_runtime.h>
#include <math.h>

// Problem constants
#define B_      32
#define S_      512
#define H_      256
#define EMB_    256
#define M_      (B_*S_)     // 16384
#define N7_     1792        // 7*H
#define NG_     2048        // reordered gate width
#define NS_     2560        // smalls: 2048 reordered + 512 fo
#define KA_     1024        // augmented K: 3H (shifted h) + EMB (emb)
#define LABEL_  16

// Layer GEMM tile
#define BM 256
#define BN 256
#define BK 64
#define NT (KA_/BK)         // 16 K-tiles
#define EBM 64

typedef __bf16 bf16x8 __attribute__((ext_vector_type(8)));
typedef float  f32x4  __attribute__((ext_vector_type(4)));
typedef unsigned short us8 __attribute__((ext_vector_type(8)));

__device__ __forceinline__ float sigf(float x){ return 1.f/(1.f+__expf(-x)); }

__device__ __forceinline__ unsigned short f2bf(float f){
    union { float f; unsigned int u; } v; v.f = f;
    unsigned int r = v.u + 0x7FFFu + ((v.u >> 16) & 1u);   // RNE
    return (unsigned short)(r >> 16);
}
__device__ __forceinline__ float bf2f(unsigned short u){
    union { unsigned int i; float f; } v; v.i = ((unsigned int)u) << 16; return v.f;
}

// ---------------------------------------------------------------------------
// Merged prep (r9 mapping — known-good): WaugT (reordered bf16), WpT
// (transposed bf16), embbf (gathered bf16 embeddings), zpage.
#define WAUG_TH (NG_*KA_/8)              // 262144
#define WPT_TH  (H_*EMB_/8)              // 8192
#define EMB_TH  (M_*EMB_/8)              // 524288
#define PREP_TH (WAUG_TH + WPT_TH + EMB_TH)

__global__ void prep_all(const float* __restrict__ Ws, const float* __restrict__ Us,
                         const float* __restrict__ ugu, const float* __restrict__ Wp,
                         const int* __restrict__ idx, const float* __restrict__ E,
                         unsigned short* __restrict__ WaugT, unsigned short* __restrict__ WpT,
                         unsigned short* __restrict__ embbf, unsigned short* __restrict__ zpage){
    long u = (long)blockIdx.x*256 + threadIdx.x;
    if(u < 512) zpage[u] = 0;
    if(u < WAUG_TH){
        int j  = (int)(u >> 7);          // 0..2047
        int kc = ((int)u & 127) * 8;     // 0..1016 step 8
        int tg = j >> 7, rem = j & 127, p = rem >> 4, t = tg*16 + (rem & 15);
        us8 o;
        if(p < 7){
            int col = p*256 + t;
            #pragma unroll
            for(int x=0;x<8;x++){
                int k = kc + x;
                float v = (k < 768) ? Ws[(long)k*N7_ + col] : Us[(long)(k-768)*N7_ + col];
                o[x] = f2bf(v);
            }
        } else {
            #pragma unroll
            for(int x=0;x<8;x++){
                int k = kc + x;
                float v = (k >= 256 && k < 512) ? ugu[(k-256)*H_ + t] : 0.f;
                o[x] = f2bf(v);
            }
        }
        *(us8*)&WaugT[(long)j*KA_ + kc] = o;
    } else if(u < WAUG_TH + WPT_TH){
        long v = u - WAUG_TH;
        int j = (int)(v >> 5), kc = ((int)v & 31)*8;
        us8 o;
        #pragma unroll
        for(int x=0;x<8;x++) o[x] = f2bf(Wp[(long)(kc+x)*H_ + j]);
        *(us8*)&WpT[(long)j*EMB_ + kc] = o;
    } else if(u < PREP_TH){
        long v = u - WAUG_TH - WPT_TH;
        int i = (int)(v >> 5), kc = ((int)v & 31)*8;
        const float* src = E + (size_t)idx[i]*EMB_ + kc;
        us8 o;
        #pragma unroll
        for(int x=0;x<8;x++) o[x] = f2bf(src[x]);
        *(us8*)&embbf[(size_t)i*EMB_ + kc] = o;
    }
}

// ---------------------------------------------------------------------------
// Embed projection via MFMA: h0(bf16) = c0(f32) = (embbf @ WpT^T + bp) * mask
// NEW: per-block h0-mean partials in the epilogue (epart[256][256]) —
// eliminates the reduce_mean_s re-read of h0.
__global__ __launch_bounds__(256, 2) void embed_mfma(
        const unsigned short* __restrict__ embbf, const unsigned short* __restrict__ WpT,
        const float* __restrict__ bp, const float* __restrict__ mask,
        unsigned short* __restrict__ h0b, float* __restrict__ c0,
        float* __restrict__ epart){
    __shared__ unsigned short As[2][EBM*32];   //  4 KB x2
    __shared__ unsigned short Bs[2][H_*32];    // 16 KB x2
    int tid = threadIdx.x, w = tid>>6, l = tid&63, fr = l&15, fq = l>>4;
    int m0 = blockIdx.x * EBM;
    f32x4 acc[4][4];
    #pragma unroll
    for(int m=0;m<4;m++)
        #pragma unroll
        for(int n=0;n<4;n++) acc[m][n] = (f32x4){0.f,0.f,0.f,0.f};

    auto stage = [&](int buf, int kt){
        {
            int row = tid >> 2;
            int k0 = ((tid & 3) ^ ((row >> 1) & 3)) * 8;
            const unsigned short* src = embbf + (size_t)(m0+row)*EMB_ + kt + k0;
            __builtin_amdgcn_global_load_lds(
                (const __attribute__((address_space(1))) unsigned int*)src,
                (__attribute__((address_space(3))) unsigned int*)(&As[buf][w*512]),
                16, 0, 0);
        }
        #pragma unroll
        for(int q=0;q<4;q++){
            int v = q*256 + tid;
            int col = v >> 2;
            int k0 = ((v & 3) ^ ((col >> 1) & 3)) * 8;
            const unsigned short* src = WpT + (size_t)col*EMB_ + kt + k0;
            __builtin_amdgcn_global_load_lds(
                (const __attribute__((address_space(1))) unsigned int*)src,
                (__attribute__((address_space(3))) unsigned int*)(&Bs[buf][(q*256 + w*64)*8]),
                16, 0, 0);
        }
    };

    stage(0, 0);
    __syncthreads();
    int cur = 0;
    for(int step=0; step<EMB_/32; step++){
        if(step+1 < EMB_/32) stage(cur^1, (step+1)*32);
        bf16x8 bfv[4];
        #pragma unroll
        for(int n=0;n<4;n++){
            int colr = w*64 + n*16 + fr;
            int slot = fq ^ ((colr >> 1) & 3);
            bfv[n] = *(const bf16x8*)(&Bs[cur][colr*32 + slot*8]);
        }
        #pragma unroll
        for(int m=0;m<4;m++){
            int rowr = m*16 + fr;
            int slot = fq ^ ((rowr >> 1) & 3);
            bf16x8 af = *(const bf16x8*)(&As[cur][rowr*32 + slot*8]);
            #pragma unroll
            for(int n=0;n<4;n++)
                acc[m][n] = __builtin_amdgcn_mfma_f32_16x16x32_bf16(af, bfv[n], acc[m][n], 0,0,0);
        }
        __syncthreads();
        cur ^= 1;
    }
    float hsum[4] = {0.f, 0.f, 0.f, 0.f};
    #pragma unroll
    for(int m=0;m<4;m++){
        #pragma unroll
        for(int j=0;j<4;j++){
            int i = m0 + m*16 + fq*4 + j;
            float mk = mask[i];
            #pragma unroll
            for(int n=0;n<4;n++){
                int col = w*64 + n*16 + fr;
                float v = (acc[m][n][j] + bp[col]) * mk;
                h0b[(size_t)i*H_ + col] = f2bf(v);
                c0 [(size_t)i*H_ + col] = v;
                hsum[n] += v;
            }
        }
    }
    // reduce over fq lanes (bits 4,5 of lane id); lanes l<16 hold col sums
    #pragma unroll
    for(int n=0;n<4;n++){
        hsum[n] += __shfl_xor(hsum[n], 16);
        hsum[n] += __shfl_xor(hsum[n], 32);
    }
    if(l < 16){
        #pragma unroll
        for(int n=0;n<4;n++)
            epart[(size_t)blockIdx.x*H_ + w*64 + n*16 + l] = hsum[n];
    }
}

// ---------------------------------------------------------------------------
// Combine embed-mean partials: g0 = cg0 = (1/S) sum of 8 row-chunks per batch.
__global__ void gcell0(const float* __restrict__ epart,
                       float* __restrict__ g0, float* __restrict__ cg0){
    int b = blockIdx.x, t = threadIdx.x;
    float s = 0.f;
    #pragma unroll
    for(int ch=0; ch<8; ch++) s += epart[(size_t)(b*8+ch)*H_ + t];
    s *= (1.f/S_);
    g0[b*H_+t]  = s;
    cg0[b*H_+t] = s;
}

// ---------------------------------------------------------------------------
// smalls[32][2560] (r8 grid: 10 x 32 blocks — TLP-bound, keep it).
// k-loops unrolled x4: same sequential accumulation order (bit-identical),
// 4 weight loads in flight.
__global__ void small_gemm(const float* __restrict__ g, const float* __restrict__ havg,
                           const float* __restrict__ Vs, const float* __restrict__ bVs,
                           const float* __restrict__ Wgw, const float* __restrict__ bgu,
                           const float* __restrict__ WgW, const float* __restrict__ UgU,
                           const float* __restrict__ bgU, float* __restrict__ smalls){
    __shared__ float gs[256], hs[256];
    int b = blockIdx.y, t0 = threadIdx.x;
    gs[t0] = g[b*H_+t0];
    hs[t0] = havg[b*H_+t0];
    __syncthreads();
    int j = blockIdx.x*256 + t0;
    float acc;
    if(j < NG_){
        int tg = j >> 7, rem = j & 127, p = rem >> 4, t = tg*16 + (rem & 15);
        if(p < 7){
            int col = p*256 + t;
            acc = bVs[col];
            #pragma unroll 4
            for(int k=0;k<H_;k++) acc += gs[k]*Vs[k*N7_+col];
        } else {
            acc = bgu[t];
            #pragma unroll 4
            for(int k=0;k<H_;k++) acc += gs[k]*Wgw[k*H_+t];
        }
    } else {
        int jj = j - NG_;
        acc = bgU[jj];
        #pragma unroll 4
        for(int k=0;k<H_;k++) acc += gs[k]*WgW[k*512+jj] + hs[k]*UgU[k*512+jj];
        acc = sigf(acc);
    }
    smalls[b*NS_+j] = acc;
}

// ---------------------------------------------------------------------------
// MFMA gates-GEMM (M=16384, N=2048, K=1024).  256x256x64 tiles, 512 thr /
// 8 waves.  Grid transposed (A L2-local); incremental staging pointers.
// EXACT r8 main loop (best measured: 95.4 us): fine per-phase interleave,
// vmcnt(0) at tile entry, stage halves 0..3 inside phases, both
// sched_barriers.  Fused SCell epilogue + GCell/h-mean partial reductions.
__global__ __launch_bounds__(512, 2) void layer_mfma(
        const unsigned short* __restrict__ hbf, const unsigned short* __restrict__ embbf,
        const unsigned short* __restrict__ WaugT, const unsigned short* __restrict__ zpage,
        const float* __restrict__ c_old, const float* __restrict__ cg_old,
        const float* __restrict__ smalls, const float* __restrict__ mask,
        unsigned short* __restrict__ hbf_new, float* __restrict__ c_new,
        float* __restrict__ lpart, float* __restrict__ apart, float* __restrict__ hpart){
    __shared__ unsigned short As[2][BM*BK];   // 32 KB x2
    __shared__ unsigned short Bs[2][BN*BK];   // 32 KB x2
    __shared__ float red[8][16][3];
    int tid = threadIdx.x;
    int w = tid >> 6, l = tid & 63;
    int fr = l & 15, fq = l >> 4;
    int wr = w >> 1, wcl = w & 1;             // wave = rows wr*64.., cols wcl*128..
    int m0 = blockIdx.x * BM;                 // grid transposed: x = M-panel
    int n0 = blockIdx.y * BN;
    int b  = m0 >> 9;

    f32x4 acc[4][8];
    #pragma unroll
    for(int m=0;m<4;m++)
        #pragma unroll
        for(int n=0;n<8;n++) acc[m][n] = (f32x4){0.f,0.f,0.f,0.f};

    // ---- hoisted per-thread staging geometry
    int rowc[2][2], k0a[2][2];
    #pragma unroll
    for(int p=0;p<2;p++)
        #pragma unroll
        for(int q=0;q<2;q++){
            int u = q*512 + tid;
            int row = p*128 + (u>>3);
            rowc[p][q] = row;
            k0a[p][q]  = ((u & 7) ^ (row & 7)) * 8;
        }
    const unsigned short* srcA[2][2];
    const unsigned short* srcB[2][2];
    #pragma unroll
    for(int hf=0;hf<2;hf++)
        #pragma unroll
        for(int q=0;q<2;q++){
            int u = q*512 + tid;
            int col = hf*128 + (u>>3);
            int k0 = ((u & 7) ^ (col & 7)) * 8;
            srcB[hf][q] = WaugT + (size_t)(n0 + col)*KA_ + k0;
        }
    auto setupA = [&](int r){
        #pragma unroll
        for(int p=0;p<2;p++)
            #pragma unroll
            for(int q=0;q<2;q++){
                int i = m0 + rowc[p][q];
                if(r < 3){
                    int si = (i & (S_-1)) + r - 1;
                    srcA[p][q] = ((unsigned)si < (unsigned)S_)
                               ? hbf + (size_t)(i + r - 1)*H_ + k0a[p][q]
                               : zpage + k0a[p][q];
                } else {
                    srcA[p][q] = embbf + (size_t)i*EMB_ + k0a[p][q];
                }
            }
    };
    auto advance = [&](){
        #pragma unroll
        for(int p=0;p<2;p++)
            #pragma unroll
            for(int q=0;q<2;q++){ srcA[p][q] += BK; srcB[p][q] += BK; }
    };
    auto stage_half = [&](int buf, int ph){   // ph 0,1 = A halves; 2,3 = B halves
        if(ph < 2){
            #pragma unroll
            for(int q=0;q<2;q++)
                __builtin_amdgcn_global_load_lds(
                    (const __attribute__((address_space(1))) unsigned int*)srcA[ph][q],
                    (__attribute__((address_space(3))) unsigned int*)
                        (&As[buf][ph*8192 + (q*512 + w*64)*8]),
                    16, 0, 0);
        } else {
            int hf = ph - 2;
            #pragma unroll
            for(int q=0;q<2;q++)
                __builtin_amdgcn_global_load_lds(
                    (const __attribute__((address_space(1))) unsigned int*)srcB[hf][q],
                    (__attribute__((address_space(3))) unsigned int*)
                        (&Bs[buf][hf*8192 + (q*512 + w*64)*8]),
                    16, 0, 0);
        }
    };

    // prologue: stage tile 0 fully into buf 0; pointers -> tile 1
    setupA(0);
    stage_half(0, 0); stage_half(0, 1); stage_half(0, 2); stage_half(0, 3);
    advance();

    bf16x8 afv[4];
    #pragma unroll 1
    for(int t=0; t<NT; ++t){
        int buf = t & 1;
        int st  = t + 1;                    // tile being staged this iter
        #pragma unroll
        for(int p=0;p<4;p++){
            int ks = p >> 1, nh = p & 1;    // kslice, n-half
            if(p == 0){
                // all 4 halves of tile t must have landed before any read
                asm volatile("s_waitcnt vmcnt(0)" ::: "memory");
                __builtin_amdgcn_s_barrier();
            }
            // 1) ds_read this phase's quadrant fragments
            if(nh == 0){
                #pragma unroll
                for(int m=0;m<4;m++){
                    int row  = wr*64 + m*16 + fr;
                    int slot = (ks*4 + fq) ^ (row & 7);
                    afv[m] = *(const bf16x8*)(&As[buf][row*BK + slot*8]);
                }
            }
            bf16x8 bfv[4];
            #pragma unroll
            for(int nn=0;nn<4;nn++){
                int col  = wcl*128 + (nh*4+nn)*16 + fr;
                int slot = (ks*4 + fq) ^ (col & 7);
                bfv[nn] = *(const bf16x8*)(&Bs[buf][col*BK + slot*8]);
            }
            // 2) stage one half-tile of t+1
            if(st < NT){
                if(p == 0 && (st & 3) == 0) setupA(st >> 2);
                stage_half(buf^1, p);
            }
            // 3) phase barrier
            __builtin_amdgcn_s_barrier();
            // 4) wait own ds_reads; fence MFMA below the wait (rule #18)
            asm volatile("s_waitcnt lgkmcnt(0)" ::: "memory");
            __builtin_amdgcn_sched_barrier(0);
            // 5) MFMA cluster on (ks, nh)
            __builtin_amdgcn_s_setprio(1);
            #pragma unroll
            for(int m=0;m<4;m++)
                #pragma unroll
                for(int nn=0;nn<4;nn++)
                    acc[m][nh*4+nn] = __builtin_amdgcn_mfma_f32_16x16x32_bf16(
                                          afv[m], bfv[nn], acc[m][nh*4+nn], 0,0,0);
            __builtin_amdgcn_s_setprio(0);
            __builtin_amdgcn_sched_barrier(0);
            // 6) phase barrier
            __builtin_amdgcn_s_barrier();
        }
        if(st < NT) advance();
    }

    // ---- fused SCell epilogue + GCell/h-mean partial reductions
    int t = (n0 >> 3) + wcl*16 + fr;
    float sm[8];
    #pragma unroll
    for(int n=0;n<8;n++) sm[n] = smalls[b*NS_ + n0 + wcl*128 + n*16 + fr];
    float cgv = cg_old[b*H_ + t];
    float lsum = 0.f, asum = 0.f, hsum = 0.f;
    #pragma unroll
    for(int m=0;m<4;m++){
        #pragma unroll
        for(int j=0;j<4;j++){
            int i = m0 + wr*64 + m*16 + fq*4 + j;
            int s = i & (S_-1);
            float gv[8];
            #pragma unroll
            for(int n=0;n<8;n++) gv[n] = acc[m][n][j] + sm[n];
            float ei=__expf(sigf(gv[0])), el=__expf(sigf(gv[1])), er=__expf(sigf(gv[2]));
            float ef=__expf(sigf(gv[3])), es=__expf(sigf(gv[4]));
            float inv = 1.f/(ei+el+er+ef+es);
            float c0v = c_old[(size_t)i*H_ + t];
            float cbv = (s>0)      ? c_old[(size_t)(i-1)*H_ + t] : 0.f;
            float cav = (s<S_-1)   ? c_old[(size_t)(i+1)*H_ + t] : 0.f;
            float tu = tanhf(gv[6]);
            float nc = (cbv*el + c0v*ef + er*cav + es*cgv + ei*tu)*inv;
            float nh2 = gv[5]*tanhf(nc);
            float mk = mask[i];
            float ncm = nc*mk, nhm = nh2*mk;
            c_new [(size_t)i*H_ + t] = ncm;
            hbf_new[(size_t)i*H_ + t] = f2bf(nhm);
            float e = __expf(sigf(gv[7]) - (1.f - mk)*1e16f);
            lsum += e;
            asum += e*c0v;
            hsum += nhm;
        }
    }
    #pragma unroll
    for(int off=16; off<64; off<<=1){
        lsum += __shfl_xor(lsum, off);
        asum += __shfl_xor(asum, off);
        hsum += __shfl_xor(hsum, off);
    }
    if(l < 16){ red[w][l][0]=lsum; red[w][l][1]=asum; red[w][l][2]=hsum; }
    __syncthreads();
    if(tid < 32){
        int wc2 = tid >> 4, fr2 = tid & 15;
        float L = 0.f, A = 0.f, Hh = 0.f;
        #pragma unroll
        for(int k=0;k<4;k++){
            L  += red[2*k + wc2][fr2][0];
            A  += red[2*k + wc2][fr2][1];
            Hh += red[2*k + wc2][fr2][2];
        }
        int tt = (n0 >> 3) + wc2*16 + fr2;
        int by = blockIdx.x;                // m-panel (grid transposed)
        lpart[by*H_ + tt] = L;
        apart[by*H_ + tt] = A;
        hpart[by*H_ + tt] = Hh;
    }
}

// ---------------------------------------------------------------------------
// Combine per-row-chunk partials: g_new, cg_new, havg (mean of h_new over S).
__global__ void gcell2x(const float* __restrict__ lpart, const float* __restrict__ apart,
                        const float* __restrict__ hpart, const float* __restrict__ cg_old,
                        const float* __restrict__ smalls,
                        float* __restrict__ g_new, float* __restrict__ cg_new,
                        float* __restrict__ havg_out){
    int b = blockIdx.x, t = threadIdx.x;
    float L = 0.f, A = 0.f, Hs = 0.f;
    for(int ci=0; ci<2; ci++){
        int by = b*2 + ci;
        L  += lpart[by*H_ + t];
        A  += apart[by*H_ + t];
        Hs += hpart[by*H_ + t];
    }
    float fg = smalls[b*NS_ + NG_ + t];
    float og = smalls[b*NS_ + NG_ + 256 + t];
    float ncg = fg*cg_old[b*H_+t] + A/L;
    g_new[b*H_+t]    = og*tanhf(ncg);
    cg_new[b*H_+t]   = ncg;
    havg_out[b*H_+t] = Hs * (1.f/S_);
}

// ---------------------------------------------------------------------------
// out[0:512] = g@Wo + bo ; out[512:528] = mean over b of the first part
__global__ void outk(const float* __restrict__ g, const float* __restrict__ Wo,
                     const float* __restrict__ bo, float* __restrict__ out){
    __shared__ float o1[B_*LABEL_];
    int t = threadIdx.x;
    if(t < B_*LABEL_){
        int b = t/LABEL_, j = t%LABEL_;
        float acc = bo[j];
        for(int k=0;k<H_;k++) acc += g[b*H_+k]*Wo[k*LABEL_+j];
        o1[t] = acc;
        out[t] = acc;
    }
    __syncthreads();
    if(t < LABEL_){
        float s = 0.f;
        for(int b=0;b<B_;b++) s += o1[b*LABEL_+t];
        out[B_*LABEL_+t] = s*(1.f/B_);
    }
}

// ---------------------------------------------------------------------------
extern "C" void kernel_launch(void* const* d_in, const int* in_sizes, int n_in,
                              void* d_out, int out_size, void* d_ws, size_t ws_size,
                              hipStream_t stream){
    const int*   node_text = (const int*)  d_in[2];
    const float* word_mask = (const float*)d_in[3];
    const float* E   = (const float*)d_in[7];
    const float* Wp  = (const float*)d_in[8];
    const float* bp  = (const float*)d_in[9];
    const float* Ws  = (const float*)d_in[10];
    const float* Us  = (const float*)d_in[11];
    const float* Vs  = (const float*)d_in[12];
    const float* bVs = (const float*)d_in[13];
    const float* WgW = (const float*)d_in[14];
    const float* Wgw = (const float*)d_in[15];
    const float* UgU = (const float*)d_in[16];
    const float* bgU = (const float*)d_in[17];
    const float* ugu = (const float*)d_in[18];
    const float* bgu = (const float*)d_in[19];
    const float* Wo  = (const float*)d_in[20];
    const float* bo  = (const float*)d_in[21];

    float* w = (float*)d_ws;
    size_t off = 0;
    auto alloc = [&](size_t nfloats){ float* p = w + off; off += nfloats; return p; };
    unsigned short* WaugT = (unsigned short*)alloc((size_t)NG_*KA_/2);   // 4 MB
    unsigned short* zpage = (unsigned short*)alloc(256);                  // 1 KB zeros
    unsigned short* WpT   = (unsigned short*)alloc((size_t)H_*EMB_/2);   // 128 KB
    unsigned short* embbf = (unsigned short*)alloc((size_t)M_*EMB_/2);   // 8.4 MB
    unsigned short* hbf[2] = { (unsigned short*)alloc((size_t)M_*H_/2),
                               (unsigned short*)alloc((size_t)M_*H_/2) };
    float* cb[2]  = { alloc((size_t)M_*H_), alloc((size_t)M_*H_) };     // 16.8 MB each
    float* lpart  = alloc((size_t)(M_/BM)*H_);
    float* apart  = alloc((size_t)(M_/BM)*H_);
    float* hpart  = alloc((size_t)(M_/BM)*H_);
    float* epart  = alloc((size_t)(M_/EBM)*H_);                          // 256 KB
    float* gb[2]  = { alloc(B_*H_), alloc(B_*H_) };
    float* cgb[2] = { alloc(B_*H_), alloc(B_*H_) };
    float* havg   = alloc(B_*H_);
    float* smalls = alloc((size_t)B_*NS_);
    // total ~ 62 MB

    prep_all<<<(PREP_TH + 255)/256, 256, 0, stream>>>(Ws, Us, ugu, Wp, node_text, E,
                                                      WaugT, WpT, embbf, zpage);
    embed_mfma<<<M_/EBM, 256, 0, stream>>>(embbf, WpT, bp, word_mask,
                                           hbf[0], cb[0], epart);
    gcell0<<<B_, 256, 0, stream>>>(epart, gb[0], cgb[0]);

    int cur = 0;
    for(int layer=0; layer<3; layer++){
        int nxt = cur ^ 1;
        const float* havg_in = (layer == 0) ? gb[0] : havg;
        small_gemm<<<dim3(NS_/256, B_), 256, 0, stream>>>(gb[cur], havg_in, Vs, bVs,
                                                          Wgw, bgu, WgW, UgU, bgU, smalls);
        layer_mfma<<<dim3(M_/BM, NG_/BN), 512, 0, stream>>>(hbf[cur], embbf, WaugT, zpage,
                                                            cb[cur], cgb[cur], smalls, word_mask,
                                                            hbf[nxt], cb[nxt],
                                                            lpart, apart, hpart);
        gcell2x<<<B_, 256, 0, stream>>>(lpart, apart, hpart, cgb[cur], smalls,
                                        gb[nxt], cgb[nxt], havg);
        cur = nxt;
    }
    outk<<<1, 512, 0, stream>>>(gb[cur], Wo, bo, (float*)d_out);
}

// Round 12
// 368.738 us; speedup vs baseline: 1.1776x; 1.1198x over previous
//
#include <hip/hip_runtime.h>
#include <math.h>

// Problem constants
#define B_      32
#define S_      512
#define H_      256
#define EMB_    256
#define M_      (B_*S_)     // 16384
#define N7_     1792        // 7*H
#define NG_     2048        // reordered gate width
#define NS_     2560        // smalls: 2048 reordered + 512 fo
#define KA_     1024        // augmented K: 3H (shifted h) + EMB (emb)
#define LABEL_  16

// Layer GEMM tile
#define BM 256
#define BN 256
#define BK 64
#define NT (KA_/BK)         // 16 K-tiles
#define EBM 64

typedef __bf16 bf16x8 __attribute__((ext_vector_type(8)));
typedef float  f32x4  __attribute__((ext_vector_type(4)));
typedef unsigned short us8 __attribute__((ext_vector_type(8)));

__device__ __forceinline__ float sigf(float x){ return 1.f/(1.f+__expf(-x)); }

__device__ __forceinline__ unsigned short f2bf(float f){
    union { float f; unsigned int u; } v; v.f = f;
    unsigned int r = v.u + 0x7FFFu + ((v.u >> 16) & 1u);   // RNE
    return (unsigned short)(r >> 16);
}
__device__ __forceinline__ float bf2f(unsigned short u){
    union { unsigned int i; float f; } v; v.i = ((unsigned int)u) << 16; return v.f;
}

// ---------------------------------------------------------------------------
// Merged prep (r9 mapping — measured-good): WaugT (reordered bf16), WpT
// (transposed bf16), embbf (gathered bf16 embeddings), zpage.
#define WAUG_TH (NG_*KA_/8)              // 262144
#define WPT_TH  (H_*EMB_/8)              // 8192
#define EMB_TH  (M_*EMB_/8)              // 524288
#define PREP_TH (WAUG_TH + WPT_TH + EMB_TH)

__global__ void prep_all(const float* __restrict__ Ws, const float* __restrict__ Us,
                         const float* __restrict__ ugu, const float* __restrict__ Wp,
                         const int* __restrict__ idx, const float* __restrict__ E,
                         unsigned short* __restrict__ WaugT, unsigned short* __restrict__ WpT,
                         unsigned short* __restrict__ embbf, unsigned short* __restrict__ zpage){
    long u = (long)blockIdx.x*256 + threadIdx.x;
    if(u < 512) zpage[u] = 0;
    if(u < WAUG_TH){
        int j  = (int)(u >> 7);          // 0..2047
        int kc = ((int)u & 127) * 8;     // 0..1016 step 8
        int tg = j >> 7, rem = j & 127, p = rem >> 4, t = tg*16 + (rem & 15);
        us8 o;
        if(p < 7){
            int col = p*256 + t;
            #pragma unroll
            for(int x=0;x<8;x++){
                int k = kc + x;
                float v = (k < 768) ? Ws[(long)k*N7_ + col] : Us[(long)(k-768)*N7_ + col];
                o[x] = f2bf(v);
            }
        } else {
            #pragma unroll
            for(int x=0;x<8;x++){
                int k = kc + x;
                float v = (k >= 256 && k < 512) ? ugu[(k-256)*H_ + t] : 0.f;
                o[x] = f2bf(v);
            }
        }
        *(us8*)&WaugT[(long)j*KA_ + kc] = o;
    } else if(u < WAUG_TH + WPT_TH){
        long v = u - WAUG_TH;
        int j = (int)(v >> 5), kc = ((int)v & 31)*8;
        us8 o;
        #pragma unroll
        for(int x=0;x<8;x++) o[x] = f2bf(Wp[(long)(kc+x)*H_ + j]);
        *(us8*)&WpT[(long)j*EMB_ + kc] = o;
    } else if(u < PREP_TH){
        long v = u - WAUG_TH - WPT_TH;
        int i = (int)(v >> 5), kc = ((int)v & 31)*8;
        const float* src = E + (size_t)idx[i]*EMB_ + kc;
        us8 o;
        #pragma unroll
        for(int x=0;x<8;x++) o[x] = f2bf(src[x]);
        *(us8*)&embbf[(size_t)i*EMB_ + kc] = o;
    }
}

// ---------------------------------------------------------------------------
// Embed projection via MFMA: h0(bf16) = c0(f32) = (embbf @ WpT^T + bp) * mask
__global__ __launch_bounds__(256, 2) void embed_mfma(
        const unsigned short* __restrict__ embbf, const unsigned short* __restrict__ WpT,
        const float* __restrict__ bp, const float* __restrict__ mask,
        unsigned short* __restrict__ h0b, float* __restrict__ c0){
    __shared__ unsigned short As[2][EBM*32];   //  4 KB x2
    __shared__ unsigned short Bs[2][H_*32];    // 16 KB x2
    int tid = threadIdx.x, w = tid>>6, l = tid&63, fr = l&15, fq = l>>4;
    int m0 = blockIdx.x * EBM;
    f32x4 acc[4][4];
    #pragma unroll
    for(int m=0;m<4;m++)
        #pragma unroll
        for(int n=0;n<4;n++) acc[m][n] = (f32x4){0.f,0.f,0.f,0.f};

    auto stage = [&](int buf, int kt){
        {
            int row = tid >> 2;
            int k0 = ((tid & 3) ^ ((row >> 1) & 3)) * 8;
            const unsigned short* src = embbf + (size_t)(m0+row)*EMB_ + kt + k0;
            __builtin_amdgcn_global_load_lds(
                (const __attribute__((address_space(1))) unsigned int*)src,
                (__attribute__((address_space(3))) unsigned int*)(&As[buf][w*512]),
                16, 0, 0);
        }
        #pragma unroll
        for(int q=0;q<4;q++){
            int v = q*256 + tid;
            int col = v >> 2;
            int k0 = ((v & 3) ^ ((col >> 1) & 3)) * 8;
            const unsigned short* src = WpT + (size_t)col*EMB_ + kt + k0;
            __builtin_amdgcn_global_load_lds(
                (const __attribute__((address_space(1))) unsigned int*)src,
                (__attribute__((address_space(3))) unsigned int*)(&Bs[buf][(q*256 + w*64)*8]),
                16, 0, 0);
        }
    };

    stage(0, 0);
    __syncthreads();
    int cur = 0;
    for(int step=0; step<EMB_/32; step++){
        if(step+1 < EMB_/32) stage(cur^1, (step+1)*32);
        bf16x8 bfv[4];
        #pragma unroll
        for(int n=0;n<4;n++){
            int colr = w*64 + n*16 + fr;
            int slot = fq ^ ((colr >> 1) & 3);
            bfv[n] = *(const bf16x8*)(&Bs[cur][colr*32 + slot*8]);
        }
        #pragma unroll
        for(int m=0;m<4;m++){
            int rowr = m*16 + fr;
            int slot = fq ^ ((rowr >> 1) & 3);
            bf16x8 af = *(const bf16x8*)(&As[cur][rowr*32 + slot*8]);
            #pragma unroll
            for(int n=0;n<4;n++)
                acc[m][n] = __builtin_amdgcn_mfma_f32_16x16x32_bf16(af, bfv[n], acc[m][n], 0,0,0);
        }
        __syncthreads();
        cur ^= 1;
    }
    #pragma unroll
    for(int m=0;m<4;m++){
        #pragma unroll
        for(int j=0;j<4;j++){
            int i = m0 + m*16 + fq*4 + j;
            float mk = mask[i];
            #pragma unroll
            for(int n=0;n<4;n++){
                int col = w*64 + n*16 + fr;
                float v = (acc[m][n][j] + bp[col]) * mk;
                h0b[(size_t)i*H_ + col] = f2bf(v);
                c0 [(size_t)i*H_ + col] = v;
            }
        }
    }
}

// ---------------------------------------------------------------------------
// mean over S of bf16 h (used once, for h0): outA/outB[b,h]
__global__ void reduce_mean_s(const unsigned short* __restrict__ h, float* __restrict__ outA,
                              float* __restrict__ outB){
    __shared__ float part[4][256];
    int b = blockIdx.x;
    int hh = threadIdx.x & 255, sg = threadIdx.x >> 8;
    float s = 0.f;
    long base = ((long)b*S_ + sg*128)*H_ + hh;
    for(int ss=0; ss<128; ss++) s += bf2f(h[base + (long)ss*H_]);
    part[sg][hh] = s;
    __syncthreads();
    if(threadIdx.x < 256){
        float t = (part[0][hh]+part[1][hh]+part[2][hh]+part[3][hh]) * (1.f/S_);
        outA[b*H_+hh] = t;
        if(outB) outB[b*H_+hh] = t;
    }
}

// ---------------------------------------------------------------------------
// smalls[32][2560] (r9-exact: plain loops, 10 x 32 blocks):
//   cols 0:2048 reordered j=(t>>4)*128+p*16+(t&15):
//   p<7 -> bVs[p*256+t] + g@Vs[:,p*256+t] ;  p==7 -> bgu[t] + g@Wgw[:,t]
// cols 2048:2560 = sigmoid(g@WgW + h_avg@UgU + bgU)  (f_g | o_g)
__global__ void small_gemm(const float* __restrict__ g, const float* __restrict__ havg,
                           const float* __restrict__ Vs, const float* __restrict__ bVs,
                           const float* __restrict__ Wgw, const float* __restrict__ bgu,
                           const float* __restrict__ WgW, const float* __restrict__ UgU,
                           const float* __restrict__ bgU, float* __restrict__ smalls){
    __shared__ float gs[256], hs[256];
    int b = blockIdx.y, t0 = threadIdx.x;
    gs[t0] = g[b*H_+t0];
    hs[t0] = havg[b*H_+t0];
    __syncthreads();
    int j = blockIdx.x*256 + t0;
    float acc;
    if(j < NG_){
        int tg = j >> 7, rem = j & 127, p = rem >> 4, t = tg*16 + (rem & 15);
        if(p < 7){
            int col = p*256 + t;
            acc = bVs[col];
            for(int k=0;k<H_;k++) acc += gs[k]*Vs[k*N7_+col];
        } else {
            acc = bgu[t];
            for(int k=0;k<H_;k++) acc += gs[k]*Wgw[k*H_+t];
        }
    } else {
        int jj = j - NG_;
        acc = bgU[jj];
        for(int k=0;k<H_;k++) acc += gs[k]*WgW[k*512+jj] + hs[k]*UgU[k*512+jj];
        acc = sigf(acc);
    }
    smalls[b*NS_+j] = acc;
}

// ---------------------------------------------------------------------------
// MFMA gates-GEMM (M=16384, N=2048, K=1024).  256x256x64 tiles, 512 thr /
// 8 waves.  Grid transposed (A L2-local); incremental staging pointers.
// r8/r11-exact main loop (measured 95.4 us twice): fine per-phase interleave,
// vmcnt(0) at tile entry, stage halves 0..3 inside phases, both
// sched_barriers.  Fused SCell epilogue + GCell/h-mean partial reductions.
__global__ __launch_bounds__(512, 2) void layer_mfma(
        const unsigned short* __restrict__ hbf, const unsigned short* __restrict__ embbf,
        const unsigned short* __restrict__ WaugT, const unsigned short* __restrict__ zpage,
        const float* __restrict__ c_old, const float* __restrict__ cg_old,
        const float* __restrict__ smalls, const float* __restrict__ mask,
        unsigned short* __restrict__ hbf_new, float* __restrict__ c_new,
        float* __restrict__ lpart, float* __restrict__ apart, float* __restrict__ hpart){
    __shared__ unsigned short As[2][BM*BK];   // 32 KB x2
    __shared__ unsigned short Bs[2][BN*BK];   // 32 KB x2
    __shared__ float red[8][16][3];
    int tid = threadIdx.x;
    int w = tid >> 6, l = tid & 63;
    int fr = l & 15, fq = l >> 4;
    int wr = w >> 1, wcl = w & 1;             // wave = rows wr*64.., cols wcl*128..
    int m0 = blockIdx.x * BM;                 // grid transposed: x = M-panel
    int n0 = blockIdx.y * BN;
    int b  = m0 >> 9;

    f32x4 acc[4][8];
    #pragma unroll
    for(int m=0;m<4;m++)
        #pragma unroll
        for(int n=0;n<8;n++) acc[m][n] = (f32x4){0.f,0.f,0.f,0.f};

    // ---- hoisted per-thread staging geometry
    int rowc[2][2], k0a[2][2];
    #pragma unroll
    for(int p=0;p<2;p++)
        #pragma unroll
        for(int q=0;q<2;q++){
            int u = q*512 + tid;
            int row = p*128 + (u>>3);
            rowc[p][q] = row;
            k0a[p][q]  = ((u & 7) ^ (row & 7)) * 8;
        }
    const unsigned short* srcA[2][2];
    const unsigned short* srcB[2][2];
    #pragma unroll
    for(int hf=0;hf<2;hf++)
        #pragma unroll
        for(int q=0;q<2;q++){
            int u = q*512 + tid;
            int col = hf*128 + (u>>3);
            int k0 = ((u & 7) ^ (col & 7)) * 8;
            srcB[hf][q] = WaugT + (size_t)(n0 + col)*KA_ + k0;
        }
    auto setupA = [&](int r){
        #pragma unroll
        for(int p=0;p<2;p++)
            #pragma unroll
            for(int q=0;q<2;q++){
                int i = m0 + rowc[p][q];
                if(r < 3){
                    int si = (i & (S_-1)) + r - 1;
                    srcA[p][q] = ((unsigned)si < (unsigned)S_)
                               ? hbf + (size_t)(i + r - 1)*H_ + k0a[p][q]
                               : zpage + k0a[p][q];
                } else {
                    srcA[p][q] = embbf + (size_t)i*EMB_ + k0a[p][q];
                }
            }
    };
    auto advance = [&](){
        #pragma unroll
        for(int p=0;p<2;p++)
            #pragma unroll
            for(int q=0;q<2;q++){ srcA[p][q] += BK; srcB[p][q] += BK; }
    };
    auto stage_half = [&](int buf, int ph){   // ph 0,1 = A halves; 2,3 = B halves
        if(ph < 2){
            #pragma unroll
            for(int q=0;q<2;q++)
                __builtin_amdgcn_global_load_lds(
                    (const __attribute__((address_space(1))) unsigned int*)srcA[ph][q],
                    (__attribute__((address_space(3))) unsigned int*)
                        (&As[buf][ph*8192 + (q*512 + w*64)*8]),
                    16, 0, 0);
        } else {
            int hf = ph - 2;
            #pragma unroll
            for(int q=0;q<2;q++)
                __builtin_amdgcn_global_load_lds(
                    (const __attribute__((address_space(1))) unsigned int*)srcB[hf][q],
                    (__attribute__((address_space(3))) unsigned int*)
                        (&Bs[buf][hf*8192 + (q*512 + w*64)*8]),
                    16, 0, 0);
        }
    };

    // prologue: stage tile 0 fully into buf 0; pointers -> tile 1
    setupA(0);
    stage_half(0, 0); stage_half(0, 1); stage_half(0, 2); stage_half(0, 3);
    advance();

    bf16x8 afv[4];
    #pragma unroll 1
    for(int t=0; t<NT; ++t){
        int buf = t & 1;
        int st  = t + 1;                    // tile being staged this iter
        #pragma unroll
        for(int p=0;p<4;p++){
            int ks = p >> 1, nh = p & 1;    // kslice, n-half
            if(p == 0){
                // all 4 halves of tile t must have landed before any read
                asm volatile("s_waitcnt vmcnt(0)" ::: "memory");
                __builtin_amdgcn_s_barrier();
            }
            // 1) ds_read this phase's quadrant fragments
            if(nh == 0){
                #pragma unroll
                for(int m=0;m<4;m++){
                    int row  = wr*64 + m*16 + fr;
                    int slot = (ks*4 + fq) ^ (row & 7);
                    afv[m] = *(const bf16x8*)(&As[buf][row*BK + slot*8]);
                }
            }
            bf16x8 bfv[4];
            #pragma unroll
            for(int nn=0;nn<4;nn++){
                int col  = wcl*128 + (nh*4+nn)*16 + fr;
                int slot = (ks*4 + fq) ^ (col & 7);
                bfv[nn] = *(const bf16x8*)(&Bs[buf][col*BK + slot*8]);
            }
            // 2) stage one half-tile of t+1
            if(st < NT){
                if(p == 0 && (st & 3) == 0) setupA(st >> 2);
                stage_half(buf^1, p);
            }
            // 3) phase barrier
            __builtin_amdgcn_s_barrier();
            // 4) wait own ds_reads; fence MFMA below the wait (rule #18)
            asm volatile("s_waitcnt lgkmcnt(0)" ::: "memory");
            __builtin_amdgcn_sched_barrier(0);
            // 5) MFMA cluster on (ks, nh)
            __builtin_amdgcn_s_setprio(1);
            #pragma unroll
            for(int m=0;m<4;m++)
                #pragma unroll
                for(int nn=0;nn<4;nn++)
                    acc[m][nh*4+nn] = __builtin_amdgcn_mfma_f32_16x16x32_bf16(
                                          afv[m], bfv[nn], acc[m][nh*4+nn], 0,0,0);
            __builtin_amdgcn_s_setprio(0);
            __builtin_amdgcn_sched_barrier(0);
            // 6) phase barrier
            __builtin_amdgcn_s_barrier();
        }
        if(st < NT) advance();
    }

    // ---- fused SCell epilogue + GCell/h-mean partial reductions
    int t = (n0 >> 3) + wcl*16 + fr;
    float sm[8];
    #pragma unroll
    for(int n=0;n<8;n++) sm[n] = smalls[b*NS_ + n0 + wcl*128 + n*16 + fr];
    float cgv = cg_old[b*H_ + t];
    float lsum = 0.f, asum = 0.f, hsum = 0.f;
    #pragma unroll
    for(int m=0;m<4;m++){
        #pragma unroll
        for(int j=0;j<4;j++){
            int i = m0 + wr*64 + m*16 + fq*4 + j;
            int s = i & (S_-1);
            float gv[8];
            #pragma unroll
            for(int n=0;n<8;n++) gv[n] = acc[m][n][j] + sm[n];
            float ei=__expf(sigf(gv[0])), el=__expf(sigf(gv[1])), er=__expf(sigf(gv[2]));
            float ef=__expf(sigf(gv[3])), es=__expf(sigf(gv[4]));
            float inv = 1.f/(ei+el+er+ef+es);
            float c0v = c_old[(size_t)i*H_ + t];
            float cbv = (s>0)      ? c_old[(size_t)(i-1)*H_ + t] : 0.f;
            float cav = (s<S_-1)   ? c_old[(size_t)(i+1)*H_ + t] : 0.f;
            float tu = tanhf(gv[6]);
            float nc = (cbv*el + c0v*ef + er*cav + es*cgv + ei*tu)*inv;
            float nh2 = gv[5]*tanhf(nc);
            float mk = mask[i];
            float ncm = nc*mk, nhm = nh2*mk;
            c_new [(size_t)i*H_ + t] = ncm;
            hbf_new[(size_t)i*H_ + t] = f2bf(nhm);
            float e = __expf(sigf(gv[7]) - (1.f - mk)*1e16f);
            lsum += e;
            asum += e*c0v;
            hsum += nhm;
        }
    }
    #pragma unroll
    for(int off=16; off<64; off<<=1){
        lsum += __shfl_xor(lsum, off);
        asum += __shfl_xor(asum, off);
        hsum += __shfl_xor(hsum, off);
    }
    if(l < 16){ red[w][l][0]=lsum; red[w][l][1]=asum; red[w][l][2]=hsum; }
    __syncthreads();
    if(tid < 32){
        int wc2 = tid >> 4, fr2 = tid & 15;
        float L = 0.f, A = 0.f, Hh = 0.f;
        #pragma unroll
        for(int k=0;k<4;k++){
            L  += red[2*k + wc2][fr2][0];
            A  += red[2*k + wc2][fr2][1];
            Hh += red[2*k + wc2][fr2][2];
        }
        int tt = (n0 >> 3) + wc2*16 + fr2;
        int by = blockIdx.x;                // m-panel (grid transposed)
        lpart[by*H_ + tt] = L;
        apart[by*H_ + tt] = A;
        hpart[by*H_ + tt] = Hh;
    }
}

// ---------------------------------------------------------------------------
// Combine per-row-chunk partials: g_new, cg_new, havg (mean of h_new over S).
__global__ void gcell2x(const float* __restrict__ lpart, const float* __restrict__ apart,
                        const float* __restrict__ hpart, const float* __restrict__ cg_old,
                        const float* __restrict__ smalls,
                        float* __restrict__ g_new, float* __restrict__ cg_new,
                        float* __restrict__ havg_out){
    int b = blockIdx.x, t = threadIdx.x;
    float L = 0.f, A = 0.f, Hs = 0.f;
    for(int ci=0; ci<2; ci++){
        int by = b*2 + ci;
        L  += lpart[by*H_ + t];
        A  += apart[by*H_ + t];
        Hs += hpart[by*H_ + t];
    }
    float fg = smalls[b*NS_ + NG_ + t];
    float og = smalls[b*NS_ + NG_ + 256 + t];
    float ncg = fg*cg_old[b*H_+t] + A/L;
    g_new[b*H_+t]    = og*tanhf(ncg);
    cg_new[b*H_+t]   = ncg;
    havg_out[b*H_+t] = Hs * (1.f/S_);
}

// ---------------------------------------------------------------------------
// out[0:512] = g@Wo + bo ; out[512:528] = mean over b of the first part
__global__ void outk(const float* __restrict__ g, const float* __restrict__ Wo,
                     const float* __restrict__ bo, float* __restrict__ out){
    __shared__ float o1[B_*LABEL_];
    int t = threadIdx.x;
    if(t < B_*LABEL_){
        int b = t/LABEL_, j = t%LABEL_;
        float acc = bo[j];
        for(int k=0;k<H_;k++) acc += g[b*H_+k]*Wo[k*LABEL_+j];
        o1[t] = acc;
        out[t] = acc;
    }
    __syncthreads();
    if(t < LABEL_){
        float s = 0.f;
        for(int b=0;b<B_;b++) s += o1[b*LABEL_+t];
        out[B_*LABEL_+t] = s*(1.f/B_);
    }
}

// ---------------------------------------------------------------------------
extern "C" void kernel_launch(void* const* d_in, const int* in_sizes, int n_in,
                              void* d_out, int out_size, void* d_ws, size_t ws_size,
                              hipStream_t stream){
    const int*   node_text = (const int*)  d_in[2];
    const float* word_mask = (const float*)d_in[3];
    const float* E   = (const float*)d_in[7];
    const float* Wp  = (const float*)d_in[8];
    const float* bp  = (const float*)d_in[9];
    const float* Ws  = (const float*)d_in[10];
    const float* Us  = (const float*)d_in[11];
    const float* Vs  = (const float*)d_in[12];
    const float* bVs = (const float*)d_in[13];
    const float* WgW = (const float*)d_in[14];
    const float* Wgw = (const float*)d_in[15];
    const float* UgU = (const float*)d_in[16];
    const float* bgU = (const float*)d_in[17];
    const float* ugu = (const float*)d_in[18];
    const float* bgu = (const float*)d_in[19];
    const float* Wo  = (const float*)d_in[20];
    const float* bo  = (const float*)d_in[21];

    float* w = (float*)d_ws;
    size_t off = 0;
    auto alloc = [&](size_t nfloats){ float* p = w + off; off += nfloats; return p; };
    unsigned short* WaugT = (unsigned short*)alloc((size_t)NG_*KA_/2);   // 4 MB
    unsigned short* zpage = (unsigned short*)alloc(256);                  // 1 KB zeros
    unsigned short* WpT   = (unsigned short*)alloc((size_t)H_*EMB_/2);   // 128 KB
    unsigned short* embbf = (unsigned short*)alloc((size_t)M_*EMB_/2);   // 8.4 MB
    unsigned short* hbf[2] = { (unsigned short*)alloc((size_t)M_*H_/2),
                               (unsigned short*)alloc((size_t)M_*H_/2) };
    float* cb[2]  = { alloc((size_t)M_*H_), alloc((size_t)M_*H_) };     // 16.8 MB each
    float* lpart  = alloc((size_t)(M_/BM)*H_);
    float* apart  = alloc((size_t)(M_/BM)*H_);
    float* hpart  = alloc((size_t)(M_/BM)*H_);
    float* gb[2]  = { alloc(B_*H_), alloc(B_*H_) };
    float* cgb[2] = { alloc(B_*H_), alloc(B_*H_) };
    float* havg   = alloc(B_*H_);
    float* smalls = alloc((size_t)B_*NS_);
    // total ~ 62 MB

    prep_all<<<(PREP_TH + 255)/256, 256, 0, stream>>>(Ws, Us, ugu, Wp, node_text, E,
                                                      WaugT, WpT, embbf, zpage);
    embed_mfma<<<M_/EBM, 256, 0, stream>>>(embbf, WpT, bp, word_mask, hbf[0], cb[0]);
    reduce_mean_s<<<B_, 1024, 0, stream>>>(hbf[0], gb[0], cgb[0]);

    int cur = 0;
    for(int layer=0; layer<3; layer++){
        int nxt = cur ^ 1;
        const float* havg_in = (layer == 0) ? gb[0] : havg;
        small_gemm<<<dim3(NS_/256, B_), 256, 0, stream>>>(gb[cur], havg_in, Vs, bVs,
                                                          Wgw, bgu, WgW, UgU, bgU, smalls);
        layer_mfma<<<dim3(M_/BM, NG_/BN), 512, 0, stream>>>(hbf[cur], embbf, WaugT, zpage,
                                                            cb[cur], cgb[cur], smalls, word_mask,
                                                            hbf[nxt], cb[nxt],
                                                            lpart, apart, hpart);
        gcell2x<<<B_, 256, 0, stream>>>(lpart, apart, hpart, cgb[cur], smalls,
                                        gb[nxt], cgb[nxt], havg);
        cur = nxt;
    }
    outk<<<1, 512, 0, stream>>>(gb[cur], Wo, bo, (float*)d_out);
}

// Round 13
// 359.365 us; speedup vs baseline: 1.2083x; 1.0261x over previous
//
#include <hip/hip_runtime.h>
#include <math.h>

// Problem constants
#define B_      32
#define S_      512
#define H_      256
#define EMB_    256
#define M_      (B_*S_)     // 16384
#define N7_     1792        // 7*H
#define NG_     2048        // reordered gate width
#define NS_     2560        // smalls: 2048 reordered + 512 fo
#define KA_     1024        // augmented K: 3H (shifted h) + EMB (emb)
#define LABEL_  16

// Layer GEMM tile
#define BM 256
#define BN 256
#define BK 64
#define NT (KA_/BK)         // 16 K-tiles
#define EBM 64

typedef __bf16 bf16x8 __attribute__((ext_vector_type(8)));
typedef float  f32x4  __attribute__((ext_vector_type(4)));
typedef unsigned short us8 __attribute__((ext_vector_type(8)));

__device__ __forceinline__ float sigf(float x){ return 1.f/(1.f+__expf(-x)); }

__device__ __forceinline__ unsigned short f2bf(float f){
    union { float f; unsigned int u; } v; v.f = f;
    unsigned int r = v.u + 0x7FFFu + ((v.u >> 16) & 1u);   // RNE
    return (unsigned short)(r >> 16);
}
__device__ __forceinline__ float bf2f(unsigned short u){
    union { unsigned int i; float f; } v; v.i = ((unsigned int)u) << 16; return v.f;
}

// ---------------------------------------------------------------------------
// Merged prep (r9 mapping — measured-good): WaugT (reordered bf16), WpT
// (transposed bf16), embbf (gathered bf16 embeddings), zpage.
#define WAUG_TH (NG_*KA_/8)              // 262144
#define WPT_TH  (H_*EMB_/8)              // 8192
#define EMB_TH  (M_*EMB_/8)              // 524288
#define PREP_TH (WAUG_TH + WPT_TH + EMB_TH)

__global__ void prep_all(const float* __restrict__ Ws, const float* __restrict__ Us,
                         const float* __restrict__ ugu, const float* __restrict__ Wp,
                         const int* __restrict__ idx, const float* __restrict__ E,
                         unsigned short* __restrict__ WaugT, unsigned short* __restrict__ WpT,
                         unsigned short* __restrict__ embbf, unsigned short* __restrict__ zpage){
    long u = (long)blockIdx.x*256 + threadIdx.x;
    if(u < 512) zpage[u] = 0;
    if(u < WAUG_TH){
        int j  = (int)(u >> 7);          // 0..2047
        int kc = ((int)u & 127) * 8;     // 0..1016 step 8
        int tg = j >> 7, rem = j & 127, p = rem >> 4, t = tg*16 + (rem & 15);
        us8 o;
        if(p < 7){
            int col = p*256 + t;
            #pragma unroll
            for(int x=0;x<8;x++){
                int k = kc + x;
                float v = (k < 768) ? Ws[(long)k*N7_ + col] : Us[(long)(k-768)*N7_ + col];
                o[x] = f2bf(v);
            }
        } else {
            #pragma unroll
            for(int x=0;x<8;x++){
                int k = kc + x;
                float v = (k >= 256 && k < 512) ? ugu[(k-256)*H_ + t] : 0.f;
                o[x] = f2bf(v);
            }
        }
        *(us8*)&WaugT[(long)j*KA_ + kc] = o;
    } else if(u < WAUG_TH + WPT_TH){
        long v = u - WAUG_TH;
        int j = (int)(v >> 5), kc = ((int)v & 31)*8;
        us8 o;
        #pragma unroll
        for(int x=0;x<8;x++) o[x] = f2bf(Wp[(long)(kc+x)*H_ + j]);
        *(us8*)&WpT[(long)j*EMB_ + kc] = o;
    } else if(u < PREP_TH){
        long v = u - WAUG_TH - WPT_TH;
        int i = (int)(v >> 5), kc = ((int)v & 31)*8;
        const float* src = E + (size_t)idx[i]*EMB_ + kc;
        us8 o;
        #pragma unroll
        for(int x=0;x<8;x++) o[x] = f2bf(src[x]);
        *(us8*)&embbf[(size_t)i*EMB_ + kc] = o;
    }
}

// ---------------------------------------------------------------------------
// Embed projection via MFMA: h0(bf16) = c0(f32) = (embbf @ WpT^T + bp) * mask
__global__ __launch_bounds__(256, 2) void embed_mfma(
        const unsigned short* __restrict__ embbf, const unsigned short* __restrict__ WpT,
        const float* __restrict__ bp, const float* __restrict__ mask,
        unsigned short* __restrict__ h0b, float* __restrict__ c0){
    __shared__ unsigned short As[2][EBM*32];   //  4 KB x2
    __shared__ unsigned short Bs[2][H_*32];    // 16 KB x2
    int tid = threadIdx.x, w = tid>>6, l = tid&63, fr = l&15, fq = l>>4;
    int m0 = blockIdx.x * EBM;
    f32x4 acc[4][4];
    #pragma unroll
    for(int m=0;m<4;m++)
        #pragma unroll
        for(int n=0;n<4;n++) acc[m][n] = (f32x4){0.f,0.f,0.f,0.f};

    auto stage = [&](int buf, int kt){
        {
            int row = tid >> 2;
            int k0 = ((tid & 3) ^ ((row >> 1) & 3)) * 8;
            const unsigned short* src = embbf + (size_t)(m0+row)*EMB_ + kt + k0;
            __builtin_amdgcn_global_load_lds(
                (const __attribute__((address_space(1))) unsigned int*)src,
                (__attribute__((address_space(3))) unsigned int*)(&As[buf][w*512]),
                16, 0, 0);
        }
        #pragma unroll
        for(int q=0;q<4;q++){
            int v = q*256 + tid;
            int col = v >> 2;
            int k0 = ((v & 3) ^ ((col >> 1) & 3)) * 8;
            const unsigned short* src = WpT + (size_t)col*EMB_ + kt + k0;
            __builtin_amdgcn_global_load_lds(
                (const __attribute__((address_space(1))) unsigned int*)src,
                (__attribute__((address_space(3))) unsigned int*)(&Bs[buf][(q*256 + w*64)*8]),
                16, 0, 0);
        }
    };

    stage(0, 0);
    __syncthreads();
    int cur = 0;
    for(int step=0; step<EMB_/32; step++){
        if(step+1 < EMB_/32) stage(cur^1, (step+1)*32);
        bf16x8 bfv[4];
        #pragma unroll
        for(int n=0;n<4;n++){
            int colr = w*64 + n*16 + fr;
            int slot = fq ^ ((colr >> 1) & 3);
            bfv[n] = *(const bf16x8*)(&Bs[cur][colr*32 + slot*8]);
        }
        #pragma unroll
        for(int m=0;m<4;m++){
            int rowr = m*16 + fr;
            int slot = fq ^ ((rowr >> 1) & 3);
            bf16x8 af = *(const bf16x8*)(&As[cur][rowr*32 + slot*8]);
            #pragma unroll
            for(int n=0;n<4;n++)
                acc[m][n] = __builtin_amdgcn_mfma_f32_16x16x32_bf16(af, bfv[n], acc[m][n], 0,0,0);
        }
        __syncthreads();
        cur ^= 1;
    }
    #pragma unroll
    for(int m=0;m<4;m++){
        #pragma unroll
        for(int j=0;j<4;j++){
            int i = m0 + m*16 + fq*4 + j;
            float mk = mask[i];
            #pragma unroll
            for(int n=0;n<4;n++){
                int col = w*64 + n*16 + fr;
                float v = (acc[m][n][j] + bp[col]) * mk;
                h0b[(size_t)i*H_ + col] = f2bf(v);
                c0 [(size_t)i*H_ + col] = v;
            }
        }
    }
}

// ---------------------------------------------------------------------------
// mean over S of bf16 h (used once, for h0): outA/outB[b,h]
__global__ void reduce_mean_s(const unsigned short* __restrict__ h, float* __restrict__ outA,
                              float* __restrict__ outB){
    __shared__ float part[4][256];
    int b = blockIdx.x;
    int hh = threadIdx.x & 255, sg = threadIdx.x >> 8;
    float s = 0.f;
    long base = ((long)b*S_ + sg*128)*H_ + hh;
    for(int ss=0; ss<128; ss++) s += bf2f(h[base + (long)ss*H_]);
    part[sg][hh] = s;
    __syncthreads();
    if(threadIdx.x < 256){
        float t = (part[0][hh]+part[1][hh]+part[2][hh]+part[3][hh]) * (1.f/S_);
        outA[b*H_+hh] = t;
        if(outB) outB[b*H_+hh] = t;
    }
}

// ---------------------------------------------------------------------------
// smalls[32][2560] (r9-exact: plain loops, 10 x 32 blocks).
__global__ void small_gemm(const float* __restrict__ g, const float* __restrict__ havg,
                           const float* __restrict__ Vs, const float* __restrict__ bVs,
                           const float* __restrict__ Wgw, const float* __restrict__ bgu,
                           const float* __restrict__ WgW, const float* __restrict__ UgU,
                           const float* __restrict__ bgU, float* __restrict__ smalls){
    __shared__ float gs[256], hs[256];
    int b = blockIdx.y, t0 = threadIdx.x;
    gs[t0] = g[b*H_+t0];
    hs[t0] = havg[b*H_+t0];
    __syncthreads();
    int j = blockIdx.x*256 + t0;
    float acc;
    if(j < NG_){
        int tg = j >> 7, rem = j & 127, p = rem >> 4, t = tg*16 + (rem & 15);
        if(p < 7){
            int col = p*256 + t;
            acc = bVs[col];
            for(int k=0;k<H_;k++) acc += gs[k]*Vs[k*N7_+col];
        } else {
            acc = bgu[t];
            for(int k=0;k<H_;k++) acc += gs[k]*Wgw[k*H_+t];
        }
    } else {
        int jj = j - NG_;
        acc = bgU[jj];
        for(int k=0;k<H_;k++) acc += gs[k]*WgW[k*512+jj] + hs[k]*UgU[k*512+jj];
        acc = sigf(acc);
    }
    smalls[b*NS_+j] = acc;
}

// ---------------------------------------------------------------------------
// MFMA gates-GEMM (M=16384, N=2048, K=1024).  256x256x64 tiles, 512 thr /
// 8 waves.  Grid transposed (A L2-local); incremental staging pointers.
// r8 loop MINUS the post-MFMA phase barrier: staging always targets buf^1,
// and the tile-entry vmcnt(0)+barrier (which every wave reaches only after
// its MFMAs consumed the ds_reads) already orders tile-t reads of buf before
// tile-t+1 staging into buf — so the second barrier per phase enforced only
// lockstep.  Removing it lets waves skew: one wave's ds_read/stage overlaps
// another's MFMA cluster (cross-wave LDS||MFMA overlap).
__global__ __launch_bounds__(512, 2) void layer_mfma(
        const unsigned short* __restrict__ hbf, const unsigned short* __restrict__ embbf,
        const unsigned short* __restrict__ WaugT, const unsigned short* __restrict__ zpage,
        const float* __restrict__ c_old, const float* __restrict__ cg_old,
        const float* __restrict__ smalls, const float* __restrict__ mask,
        unsigned short* __restrict__ hbf_new, float* __restrict__ c_new,
        float* __restrict__ lpart, float* __restrict__ apart, float* __restrict__ hpart){
    __shared__ unsigned short As[2][BM*BK];   // 32 KB x2
    __shared__ unsigned short Bs[2][BN*BK];   // 32 KB x2
    __shared__ float red[8][16][3];
    int tid = threadIdx.x;
    int w = tid >> 6, l = tid & 63;
    int fr = l & 15, fq = l >> 4;
    int wr = w >> 1, wcl = w & 1;             // wave = rows wr*64.., cols wcl*128..
    int m0 = blockIdx.x * BM;                 // grid transposed: x = M-panel
    int n0 = blockIdx.y * BN;
    int b  = m0 >> 9;

    f32x4 acc[4][8];
    #pragma unroll
    for(int m=0;m<4;m++)
        #pragma unroll
        for(int n=0;n<8;n++) acc[m][n] = (f32x4){0.f,0.f,0.f,0.f};

    // ---- hoisted per-thread staging geometry
    int rowc[2][2], k0a[2][2];
    #pragma unroll
    for(int p=0;p<2;p++)
        #pragma unroll
        for(int q=0;q<2;q++){
            int u = q*512 + tid;
            int row = p*128 + (u>>3);
            rowc[p][q] = row;
            k0a[p][q]  = ((u & 7) ^ (row & 7)) * 8;
        }
    const unsigned short* srcA[2][2];
    const unsigned short* srcB[2][2];
    #pragma unroll
    for(int hf=0;hf<2;hf++)
        #pragma unroll
        for(int q=0;q<2;q++){
            int u = q*512 + tid;
            int col = hf*128 + (u>>3);
            int k0 = ((u & 7) ^ (col & 7)) * 8;
            srcB[hf][q] = WaugT + (size_t)(n0 + col)*KA_ + k0;
        }
    auto setupA = [&](int r){
        #pragma unroll
        for(int p=0;p<2;p++)
            #pragma unroll
            for(int q=0;q<2;q++){
                int i = m0 + rowc[p][q];
                if(r < 3){
                    int si = (i & (S_-1)) + r - 1;
                    srcA[p][q] = ((unsigned)si < (unsigned)S_)
                               ? hbf + (size_t)(i + r - 1)*H_ + k0a[p][q]
                               : zpage + k0a[p][q];
                } else {
                    srcA[p][q] = embbf + (size_t)i*EMB_ + k0a[p][q];
                }
            }
    };
    auto advance = [&](){
        #pragma unroll
        for(int p=0;p<2;p++)
            #pragma unroll
            for(int q=0;q<2;q++){ srcA[p][q] += BK; srcB[p][q] += BK; }
    };
    auto stage_half = [&](int buf, int ph){   // ph 0,1 = A halves; 2,3 = B halves
        if(ph < 2){
            #pragma unroll
            for(int q=0;q<2;q++)
                __builtin_amdgcn_global_load_lds(
                    (const __attribute__((address_space(1))) unsigned int*)srcA[ph][q],
                    (__attribute__((address_space(3))) unsigned int*)
                        (&As[buf][ph*8192 + (q*512 + w*64)*8]),
                    16, 0, 0);
        } else {
            int hf = ph - 2;
            #pragma unroll
            for(int q=0;q<2;q++)
                __builtin_amdgcn_global_load_lds(
                    (const __attribute__((address_space(1))) unsigned int*)srcB[hf][q],
                    (__attribute__((address_space(3))) unsigned int*)
                        (&Bs[buf][hf*8192 + (q*512 + w*64)*8]),
                    16, 0, 0);
        }
    };

    // prologue: stage tile 0 fully into buf 0; pointers -> tile 1
    setupA(0);
    stage_half(0, 0); stage_half(0, 1); stage_half(0, 2); stage_half(0, 3);
    advance();

    bf16x8 afv[4];
    #pragma unroll 1
    for(int t=0; t<NT; ++t){
        int buf = t & 1;
        int st  = t + 1;                    // tile being staged this iter
        #pragma unroll
        for(int p=0;p<4;p++){
            int ks = p >> 1, nh = p & 1;    // kslice, n-half
            if(p == 0){
                // all 4 halves of tile t must have landed before any read
                asm volatile("s_waitcnt vmcnt(0)" ::: "memory");
                __builtin_amdgcn_s_barrier();
            }
            // 1) ds_read this phase's quadrant fragments
            if(nh == 0){
                #pragma unroll
                for(int m=0;m<4;m++){
                    int row  = wr*64 + m*16 + fr;
                    int slot = (ks*4 + fq) ^ (row & 7);
                    afv[m] = *(const bf16x8*)(&As[buf][row*BK + slot*8]);
                }
            }
            bf16x8 bfv[4];
            #pragma unroll
            for(int nn=0;nn<4;nn++){
                int col  = wcl*128 + (nh*4+nn)*16 + fr;
                int slot = (ks*4 + fq) ^ (col & 7);
                bfv[nn] = *(const bf16x8*)(&Bs[buf][col*BK + slot*8]);
            }
            // 2) stage one half-tile of t+1 (targets buf^1 — no hazard with
            //    concurrent readers of buf)
            if(st < NT){
                if(p == 0 && (st & 3) == 0) setupA(st >> 2);
                stage_half(buf^1, p);
            }
            // 3) phase barrier (pre-MFMA; also orders this phase's ds_reads
            //    block-wide before anyone's next-tile staging can pass the
            //    tile-entry barrier)
            __builtin_amdgcn_s_barrier();
            // 4) wait own ds_reads; fence MFMA below the wait (rule #18)
            asm volatile("s_waitcnt lgkmcnt(0)" ::: "memory");
            __builtin_amdgcn_sched_barrier(0);
            // 5) MFMA cluster on (ks, nh)
            __builtin_amdgcn_s_setprio(1);
            #pragma unroll
            for(int m=0;m<4;m++)
                #pragma unroll
                for(int nn=0;nn<4;nn++)
                    acc[m][nh*4+nn] = __builtin_amdgcn_mfma_f32_16x16x32_bf16(
                                          afv[m], bfv[nn], acc[m][nh*4+nn], 0,0,0);
            __builtin_amdgcn_s_setprio(0);
            __builtin_amdgcn_sched_barrier(0);
            // (post-MFMA barrier removed — see kernel comment)
        }
        if(st < NT) advance();
    }

    // ---- fused SCell epilogue + GCell/h-mean partial reductions
    int t = (n0 >> 3) + wcl*16 + fr;
    float sm[8];
    #pragma unroll
    for(int n=0;n<8;n++) sm[n] = smalls[b*NS_ + n0 + wcl*128 + n*16 + fr];
    float cgv = cg_old[b*H_ + t];
    float lsum = 0.f, asum = 0.f, hsum = 0.f;
    #pragma unroll
    for(int m=0;m<4;m++){
        #pragma unroll
        for(int j=0;j<4;j++){
            int i = m0 + wr*64 + m*16 + fq*4 + j;
            int s = i & (S_-1);
            float gv[8];
            #pragma unroll
            for(int n=0;n<8;n++) gv[n] = acc[m][n][j] + sm[n];
            float ei=__expf(sigf(gv[0])), el=__expf(sigf(gv[1])), er=__expf(sigf(gv[2]));
            float ef=__expf(sigf(gv[3])), es=__expf(sigf(gv[4]));
            float inv = 1.f/(ei+el+er+ef+es);
            float c0v = c_old[(size_t)i*H_ + t];
            float cbv = (s>0)      ? c_old[(size_t)(i-1)*H_ + t] : 0.f;
            float cav = (s<S_-1)   ? c_old[(size_t)(i+1)*H_ + t] : 0.f;
            float tu = tanhf(gv[6]);
            float nc = (cbv*el + c0v*ef + er*cav + es*cgv + ei*tu)*inv;
            float nh2 = gv[5]*tanhf(nc);
            float mk = mask[i];
            float ncm = nc*mk, nhm = nh2*mk;
            c_new [(size_t)i*H_ + t] = ncm;
            hbf_new[(size_t)i*H_ + t] = f2bf(nhm);
            float e = __expf(sigf(gv[7]) - (1.f - mk)*1e16f);
            lsum += e;
            asum += e*c0v;
            hsum += nhm;
        }
    }
    #pragma unroll
    for(int off=16; off<64; off<<=1){
        lsum += __shfl_xor(lsum, off);
        asum += __shfl_xor(asum, off);
        hsum += __shfl_xor(hsum, off);
    }
    if(l < 16){ red[w][l][0]=lsum; red[w][l][1]=asum; red[w][l][2]=hsum; }
    __syncthreads();
    if(tid < 32){
        int wc2 = tid >> 4, fr2 = tid & 15;
        float L = 0.f, A = 0.f, Hh = 0.f;
        #pragma unroll
        for(int k=0;k<4;k++){
            L  += red[2*k + wc2][fr2][0];
            A  += red[2*k + wc2][fr2][1];
            Hh += red[2*k + wc2][fr2][2];
        }
        int tt = (n0 >> 3) + wc2*16 + fr2;
        int by = blockIdx.x;                // m-panel (grid transposed)
        lpart[by*H_ + tt] = L;
        apart[by*H_ + tt] = A;
        hpart[by*H_ + tt] = Hh;
    }
}

// ---------------------------------------------------------------------------
// Combine per-row-chunk partials: g_new, cg_new, havg (mean of h_new over S).
__global__ void gcell2x(const float* __restrict__ lpart, const float* __restrict__ apart,
                        const float* __restrict__ hpart, const float* __restrict__ cg_old,
                        const float* __restrict__ smalls,
                        float* __restrict__ g_new, float* __restrict__ cg_new,
                        float* __restrict__ havg_out){
    int b = blockIdx.x, t = threadIdx.x;
    float L = 0.f, A = 0.f, Hs = 0.f;
    for(int ci=0; ci<2; ci++){
        int by = b*2 + ci;
        L  += lpart[by*H_ + t];
        A  += apart[by*H_ + t];
        Hs += hpart[by*H_ + t];
    }
    float fg = smalls[b*NS_ + NG_ + t];
    float og = smalls[b*NS_ + NG_ + 256 + t];
    float ncg = fg*cg_old[b*H_+t] + A/L;
    g_new[b*H_+t]    = og*tanhf(ncg);
    cg_new[b*H_+t]   = ncg;
    havg_out[b*H_+t] = Hs * (1.f/S_);
}

// ---------------------------------------------------------------------------
// out[0:512] = g@Wo + bo ; out[512:528] = mean over b of the first part
__global__ void outk(const float* __restrict__ g, const float* __restrict__ Wo,
                     const float* __restrict__ bo, float* __restrict__ out){
    __shared__ float o1[B_*LABEL_];
    int t = threadIdx.x;
    if(t < B_*LABEL_){
        int b = t/LABEL_, j = t%LABEL_;
        float acc = bo[j];
        for(int k=0;k<H_;k++) acc += g[b*H_+k]*Wo[k*LABEL_+j];
        o1[t] = acc;
        out[t] = acc;
    }
    __syncthreads();
    if(t < LABEL_){
        float s = 0.f;
        for(int b=0;b<B_;b++) s += o1[b*LABEL_+t];
        out[B_*LABEL_+t] = s*(1.f/B_);
    }
}

// ---------------------------------------------------------------------------
extern "C" void kernel_launch(void* const* d_in, const int* in_sizes, int n_in,
                              void* d_out, int out_size, void* d_ws, size_t ws_size,
                              hipStream_t stream){
    const int*   node_text = (const int*)  d_in[2];
    const float* word_mask = (const float*)d_in[3];
    const float* E   = (const float*)d_in[7];
    const float* Wp  = (const float*)d_in[8];
    const float* bp  = (const float*)d_in[9];
    const float* Ws  = (const float*)d_in[10];
    const float* Us  = (const float*)d_in[11];
    const float* Vs  = (const float*)d_in[12];
    const float* bVs = (const float*)d_in[13];
    const float* WgW = (const float*)d_in[14];
    const float* Wgw = (const float*)d_in[15];
    const float* UgU = (const float*)d_in[16];
    const float* bgU = (const float*)d_in[17];
    const float* ugu = (const float*)d_in[18];
    const float* bgu = (const float*)d_in[19];
    const float* Wo  = (const float*)d_in[20];
    const float* bo  = (const float*)d_in[21];

    float* w = (float*)d_ws;
    size_t off = 0;
    auto alloc = [&](size_t nfloats){ float* p = w + off; off += nfloats; return p; };
    unsigned short* WaugT = (unsigned short*)alloc((size_t)NG_*KA_/2);   // 4 MB
    unsigned short* zpage = (unsigned short*)alloc(256);                  // 1 KB zeros
    unsigned short* WpT   = (unsigned short*)alloc((size_t)H_*EMB_/2);   // 128 KB
    unsigned short* embbf = (unsigned short*)alloc((size_t)M_*EMB_/2);   // 8.4 MB
    unsigned short* hbf[2] = { (unsigned short*)alloc((size_t)M_*H_/2),
                               (unsigned short*)alloc((size_t)M_*H_/2) };
    float* cb[2]  = { alloc((size_t)M_*H_), alloc((size_t)M_*H_) };     // 16.8 MB each
    float* lpart  = alloc((size_t)(M_/BM)*H_);
    float* apart  = alloc((size_t)(M_/BM)*H_);
    float* hpart  = alloc((size_t)(M_/BM)*H_);
    float* gb[2]  = { alloc(B_*H_), alloc(B_*H_) };
    float* cgb[2] = { alloc(B_*H_), alloc(B_*H_) };
    float* havg   = alloc(B_*H_);
    float* smalls = alloc((size_t)B_*NS_);
    // total ~ 62 MB

    prep_all<<<(PREP_TH + 255)/256, 256, 0, stream>>>(Ws, Us, ugu, Wp, node_text, E,
                                                      WaugT, WpT, embbf, zpage);
    embed_mfma<<<M_/EBM, 256, 0, stream>>>(embbf, WpT, bp, word_mask, hbf[0], cb[0]);
    reduce_mean_s<<<B_, 1024, 0, stream>>>(hbf[0], gb[0], cgb[0]);

    int cur = 0;
    for(int layer=0; layer<3; layer++){
        int nxt = cur ^ 1;
        const float* havg_in = (layer == 0) ? gb[0] : havg;
        small_gemm<<<dim3(NS_/256, B_), 256, 0, stream>>>(gb[cur], havg_in, Vs, bVs,
                                                          Wgw, bgu, WgW, UgU, bgU, smalls);
        layer_mfma<<<dim3(M_/BM, NG_/BN), 512, 0, stream>>>(hbf[cur], embbf, WaugT, zpage,
                                                            cb[cur], cgb[cur], smalls, word_mask,
                                                            hbf[nxt], cb[nxt],
                                                            lpart, apart, hpart);
        gcell2x<<<B_, 256, 0, stream>>>(lpart, apart, hpart, cgb[cur], smalls,
                                        gb[nxt], cgb[nxt], havg);
        cur = nxt;
    }
    outk<<<1, 512, 0, stream>>>(gb[cur], Wo, bo, (float*)d_out);
}